// Round 1
// baseline (854.717 us; speedup 1.0000x reference)
//
#include <hip/hip_runtime.h>
#include <hip/hip_bf16.h>
#include <math.h>

typedef __bf16 bf16;
typedef __bf16 bf16x8 __attribute__((ext_vector_type(8)));
typedef float f32x4 __attribute__((ext_vector_type(4)));

#define S_LEN 2048
#define HID_D 4096
#define NH 32
#define NKV 8
#define HD 128
// D^-0.5 * log2(e): softmax computed in exp2 domain
#define SCALE_LOG2 (0.08838834764831843f * 1.4426950408889634f)

__device__ __forceinline__ void gload_lds16(const void* g, void* lds) {
  __builtin_amdgcn_global_load_lds((__attribute__((address_space(1))) void*)g,
                                   (__attribute__((address_space(3))) void*)lds, 16, 0, 0);
}

// ---------------- f32 -> bf16 convert (vectorized, grid-stride) ----------------
__global__ __launch_bounds__(256) void cvt_kernel(const float* __restrict__ in,
                                                  bf16* __restrict__ out, int n8) {
  int i = blockIdx.x * blockDim.x + threadIdx.x;
  int stride = gridDim.x * blockDim.x;
  for (; i < n8; i += stride) {
    const float4* p = (const float4*)in + 2 * (size_t)i;
    float4 a = p[0], b = p[1];
    bf16x8 o;
    o[0] = (bf16)a.x; o[1] = (bf16)a.y; o[2] = (bf16)a.z; o[3] = (bf16)a.w;
    o[4] = (bf16)b.x; o[5] = (bf16)b.y; o[6] = (bf16)b.z; o[7] = (bf16)b.w;
    *((bf16x8*)out + i) = o;
  }
}

// ---------------- bf16 NT GEMM: C[M][N] = A[M][K] * B[N][K]^T, C in f32 --------
// m97 structure: 128x128 tile, BK=32, 4 waves (2x2), global_load_lds width 16.
__global__ __launch_bounds__(256) void gemm_bt(const bf16* __restrict__ A,
                                               const bf16* __restrict__ B,
                                               float* __restrict__ C,
                                               int M, int N, int K) {
  __shared__ __align__(16) bf16 As[128 * 32];
  __shared__ __align__(16) bf16 Bs[128 * 32];
  const int t = threadIdx.x, l = t & 63, w = t >> 6;
  const int wm = w >> 1, wn = w & 1;
  const int l15 = l & 15, lg = l >> 4;
  const int m0 = blockIdx.y * 128, n0 = blockIdx.x * 128;

  f32x4 acc[4][4] = {};

  for (int k0 = 0; k0 < K; k0 += 32) {
#pragma unroll
    for (int j = 0; j < 2; j++) {
      int c = j * 256 + t;                 // 16B chunk index within 8KB tile
      int row = c >> 2, kc = (c & 3) * 8;  // 4 chunks per 32-elem row
      gload_lds16(A + (size_t)(m0 + row) * K + k0 + kc, As + (size_t)(j * 256 + w * 64) * 8);
      gload_lds16(B + (size_t)(n0 + row) * K + k0 + kc, Bs + (size_t)(j * 256 + w * 64) * 8);
    }
    __syncthreads();  // drains vmcnt for global_load_lds

    bf16x8 af[4], bfr[4];
#pragma unroll
    for (int i = 0; i < 4; i++)
      af[i] = *(const bf16x8*)(As + (wm * 64 + i * 16 + l15) * 32 + lg * 8);
#pragma unroll
    for (int j = 0; j < 4; j++)
      bfr[j] = *(const bf16x8*)(Bs + (wn * 64 + j * 16 + l15) * 32 + lg * 8);
#pragma unroll
    for (int i = 0; i < 4; i++)
#pragma unroll
      for (int j = 0; j < 4; j++)
        acc[i][j] = __builtin_amdgcn_mfma_f32_16x16x32_bf16(af[i], bfr[j], acc[i][j], 0, 0, 0);
    __syncthreads();
  }

#pragma unroll
  for (int i = 0; i < 4; i++) {
    int row = m0 + wm * 64 + i * 16 + lg * 4;  // C/D layout: row=(l>>4)*4+reg, col=l&15
#pragma unroll
    for (int j = 0; j < 4; j++) {
      int col = n0 + wn * 64 + j * 16 + l15;
      float* Cp = C + (size_t)row * N + col;
#pragma unroll
      for (int r = 0; r < 4; r++) Cp[(size_t)r * N] = acc[i][j][r];
    }
  }
}

// ---------------- fused RMSNorm + RoPE + layout kernel -------------------------
// QKV f32 row [6144] = [q 4096 | k 1024 | v 1024]
// Outputs: Qb[NH][S][HD], Kb[NKV][S][HD], Vt[NKV][HD][S] (bf16)
__global__ __launch_bounds__(256) void prep_kernel(const float* __restrict__ QKV,
                                                   const float* __restrict__ qw,
                                                   const float* __restrict__ kw,
                                                   const int* __restrict__ pos_ids,
                                                   bf16* __restrict__ Qb,
                                                   bf16* __restrict__ Kb,
                                                   bf16* __restrict__ Vt) {
  __shared__ __align__(16) float row[6144];
  __shared__ float cs[64];  // cos[0..31], sin[32..63]
  __shared__ float red[8];
  const int s = blockIdx.x, t = threadIdx.x;

  const float4* src = (const float4*)(QKV + (size_t)s * 6144);
#pragma unroll
  for (int i = 0; i < 6; i++) ((float4*)row)[t + i * 256] = src[t + i * 256];

  if (t < 32) {
    float p = (float)pos_ids[s];
    float ang = p * powf(10000.0f, -(float)t * (1.0f / 32.0f));
    float sn, cn;
    sincosf(ang, &sn, &cn);
    cs[t] = cn;
    cs[32 + t] = sn;
  }
  __syncthreads();

  float aq = 0.f, ak = 0.f;
  for (int i = t; i < 4096; i += 256) { float v = row[i]; aq += v * v; }
  for (int i = 4096 + t; i < 5120; i += 256) { float v = row[i]; ak += v * v; }
#pragma unroll
  for (int off = 32; off; off >>= 1) {
    aq += __shfl_down(aq, off);
    ak += __shfl_down(ak, off);
  }
  if ((t & 63) == 0) { red[t >> 6] = aq; red[4 + (t >> 6)] = ak; }
  __syncthreads();
  const float scq = rsqrtf((red[0] + red[1] + red[2] + red[3]) * (1.0f / 4096.0f) + 1e-6f);
  const float sck = rsqrtf((red[4] + red[5] + red[6] + red[7]) * (1.0f / 1024.0f) + 1e-6f);

  // q: norm + rope
  for (int e = t; e < 4096; e += 256) {
    int hh = e >> 7, d = e & 127;
    float val = row[e] * scq * qw[e];
    float o;
    if (d < 32)       o = val * cs[d] - (row[e + 32] * scq * qw[e + 32]) * cs[32 + d];
    else if (d < 64)  o = val * cs[d - 32] + (row[e - 32] * scq * qw[e - 32]) * cs[d];
    else              o = val;
    Qb[((size_t)hh * S_LEN + s) * HD + d] = (bf16)o;
  }
  // k: norm + rope
  for (int e = t; e < 1024; e += 256) {
    int hh = e >> 7, d = e & 127;
    int ri = 4096 + e;
    float val = row[ri] * sck * kw[e];
    float o;
    if (d < 32)       o = val * cs[d] - (row[ri + 32] * sck * kw[e + 32]) * cs[32 + d];
    else if (d < 64)  o = val * cs[d - 32] + (row[ri - 32] * sck * kw[e - 32]) * cs[d];
    else              o = val;
    Kb[((size_t)hh * S_LEN + s) * HD + d] = (bf16)o;
  }
  // v: transpose write
  for (int e = t; e < 1024; e += 256) {
    int hh = e >> 7, d = e & 127;
    Vt[((size_t)hh * HD + d) * S_LEN + s] = (bf16)row[5120 + e];
  }
}

// ---------------- flash attention (GQA, causal) --------------------------------
// grid (S/64, NH), 256 threads = 4 independent waves, each owns 16 q rows.
// KVBLK=32. K/V read straight from global (L2-resident). P relayout via LDS.
__global__ __launch_bounds__(256) void attn_kernel(const bf16* __restrict__ Qb,
                                                   const bf16* __restrict__ Kb,
                                                   const bf16* __restrict__ Vt,
                                                   bf16* __restrict__ Ctx) {
  __shared__ __align__(16) bf16 P[4][16][40];  // pitch 40 bf16 = 80B (bank spread)
  const int t = threadIdx.x, l = t & 63, w = t >> 6;
  const int l15 = l & 15, lg = l >> 4;
  const int h = blockIdx.y;
  const int q0 = blockIdx.x * 64 + w * 16;

  const bf16* Qh = Qb + ((size_t)h * S_LEN + q0) * HD;
  const bf16* Kh = Kb + (size_t)(h >> 2) * S_LEN * HD;
  const bf16* Vh = Vt + (size_t)(h >> 2) * HD * S_LEN;

  bf16x8 qf[4];
#pragma unroll
  for (int kk = 0; kk < 4; kk++)
    qf[kk] = *(const bf16x8*)(Qh + l15 * HD + kk * 32 + lg * 8);

  f32x4 O[8] = {};
  float m[4], lsum[4];
#pragma unroll
  for (int r = 0; r < 4; r++) { m[r] = -1e30f; lsum[r] = 0.f; }

  const int ntiles = ((q0 + 15) >> 5) + 1;
  for (int tt = 0; tt < ntiles; tt++) {
    const int kv0 = tt * 32;
    f32x4 sc[2] = {};
#pragma unroll
    for (int nt = 0; nt < 2; nt++) {
      const bf16* Kp = Kh + (size_t)(kv0 + nt * 16 + l15) * HD + lg * 8;
#pragma unroll
      for (int kk = 0; kk < 4; kk++) {
        bf16x8 kf = *(const bf16x8*)(Kp + kk * 32);
        sc[nt] = __builtin_amdgcn_mfma_f32_16x16x32_bf16(qf[kk], kf, sc[nt], 0, 0, 0);
      }
    }
    float sv[2][4];
    const bool needmask = (kv0 + 31 > q0);
#pragma unroll
    for (int nt = 0; nt < 2; nt++)
#pragma unroll
      for (int r = 0; r < 4; r++) {
        float x = sc[nt][r] * SCALE_LOG2;
        if (needmask) {
          int kv = kv0 + nt * 16 + l15;
          int qr = q0 + lg * 4 + r;
          if (kv > qr) x = -1e30f;
        }
        sv[nt][r] = x;
      }
    float mn[4], al[4];
#pragma unroll
    for (int r = 0; r < 4; r++) {
      float x = fmaxf(sv[0][r], sv[1][r]);
      x = fmaxf(x, __shfl_xor(x, 1));
      x = fmaxf(x, __shfl_xor(x, 2));
      x = fmaxf(x, __shfl_xor(x, 4));
      x = fmaxf(x, __shfl_xor(x, 8));
      mn[r] = fmaxf(m[r], x);
      al[r] = exp2f(m[r] - mn[r]);
      m[r] = mn[r];
    }
#pragma unroll
    for (int nt = 0; nt < 2; nt++)
#pragma unroll
      for (int r = 0; r < 4; r++) sv[nt][r] = exp2f(sv[nt][r] - mn[r]);
#pragma unroll
    for (int r = 0; r < 4; r++) {
      float x = sv[0][r] + sv[1][r];
      x += __shfl_xor(x, 1);
      x += __shfl_xor(x, 2);
      x += __shfl_xor(x, 4);
      x += __shfl_xor(x, 8);
      lsum[r] = lsum[r] * al[r] + x;
    }
#pragma unroll
    for (int dt = 0; dt < 8; dt++)
#pragma unroll
      for (int r = 0; r < 4; r++) O[dt][r] *= al[r];
    // P (C-layout) -> LDS -> A-layout fragment
#pragma unroll
    for (int nt = 0; nt < 2; nt++)
#pragma unroll
      for (int r = 0; r < 4; r++) P[w][lg * 4 + r][nt * 16 + l15] = (bf16)sv[nt][r];
    asm volatile("s_waitcnt lgkmcnt(0)" ::: "memory");
    bf16x8 pa = *(const bf16x8*)&P[w][l15][lg * 8];
#pragma unroll
    for (int dt = 0; dt < 8; dt++) {
      bf16x8 vf = *(const bf16x8*)(Vh + (size_t)(dt * 16 + l15) * S_LEN + kv0 + lg * 8);
      O[dt] = __builtin_amdgcn_mfma_f32_16x16x32_bf16(pa, vf, O[dt], 0, 0, 0);
    }
  }

#pragma unroll
  for (int r = 0; r < 4; r++) {
    float inv = 1.0f / lsum[r];
    bf16* Cp = Ctx + (size_t)(q0 + lg * 4 + r) * HID_D + h * HD + l15;
#pragma unroll
    for (int dt = 0; dt < 8; dt++) Cp[dt * 16] = (bf16)(O[dt][r] * inv);
  }
}

// ---------------- host launcher ------------------------------------------------
extern "C" void kernel_launch(void* const* d_in, const int* in_sizes, int n_in,
                              void* d_out, int out_size, void* d_ws, size_t ws_size,
                              hipStream_t stream) {
  const float* X  = (const float*)d_in[0];
  const float* Wq = (const float*)d_in[1];
  const float* Wk = (const float*)d_in[2];
  const float* Wv = (const float*)d_in[3];
  const float* Wo = (const float*)d_in[4];
  const float* qw = (const float*)d_in[5];
  const float* kw = (const float*)d_in[6];
  const int* pos  = (const int*)d_in[7];

  char* ws = (char*)d_ws;
  bf16* Xb    = (bf16*)ws;                         // 16 MB
  bf16* Wqkvb = (bf16*)(ws + (16ll << 20));        // 48 MB: Wq|Wk|Wv contiguous
  bf16* Wob   = Wqkvb;                             // reused after GEMM1
  float* QKV  = (float*)(ws + (64ll << 20));       // 48 MB
  bf16* Ctx   = (bf16*)(ws + (64ll << 20));        // aliases QKV (after prep)
  bf16* Qb    = (bf16*)(ws + (112ll << 20));       // 16 MB
  bf16* Kb    = (bf16*)(ws + (128ll << 20));       // 4 MB
  bf16* Vt    = (bf16*)(ws + (132ll << 20));       // 4 MB

  // bf16 conversions
  cvt_kernel<<<2048, 256, 0, stream>>>(X, Xb, S_LEN * HID_D / 8);
  cvt_kernel<<<2048, 256, 0, stream>>>(Wq, Wqkvb, 4096 * 4096 / 8);
  cvt_kernel<<<512, 256, 0, stream>>>(Wk, Wqkvb + 4096 * 4096, 1024 * 4096 / 8);
  cvt_kernel<<<512, 256, 0, stream>>>(Wv, Wqkvb + 5120 * 4096, 1024 * 4096 / 8);

  // fused QKV projection: [2048 x 6144] = Xb [2048x4096] @ Wqkvb^T
  gemm_bt<<<dim3(48, 16), 256, 0, stream>>>(Xb, Wqkvb, QKV, S_LEN, 6144, HID_D);

  // Wo conversion (overwrites Wqkvb region; safe: stream-ordered after GEMM1)
  cvt_kernel<<<2048, 256, 0, stream>>>(Wo, Wob, 4096 * 4096 / 8);

  // RMSNorm + RoPE + attention layouts
  prep_kernel<<<S_LEN, 256, 0, stream>>>(QKV, qw, kw, pos, Qb, Kb, Vt);

  // flash attention (Ctx overwrites QKV region; safe after prep)
  attn_kernel<<<dim3(S_LEN / 64, NH), 256, 0, stream>>>(Qb, Kb, Vt, Ctx);

  // output projection: d_out [2048x4096] = Ctx @ Wob^T
  gemm_bt<<<dim3(32, 16), 256, 0, stream>>>(Ctx, Wob, (float*)d_out, S_LEN, HID_D, HID_D);
}

// Round 2
// 603.028 us; speedup vs baseline: 1.4174x; 1.4174x over previous
//
#include <hip/hip_runtime.h>
#include <hip/hip_bf16.h>
#include <math.h>

typedef __bf16 bf16;
typedef __bf16 bf16x8 __attribute__((ext_vector_type(8)));
typedef float f32x4 __attribute__((ext_vector_type(4)));

#define S_LEN 2048
#define HID_D 4096
#define NH 32
#define NKV 8
#define HD 128
// D^-0.5 * log2(e): softmax computed in exp2 domain
#define SCALE_LOG2 (0.08838834764831843f * 1.4426950408889634f)

__device__ __forceinline__ void gload_lds16(const void* g, void* lds) {
  __builtin_amdgcn_global_load_lds((__attribute__((address_space(1))) void*)g,
                                   (__attribute__((address_space(3))) void*)lds, 16, 0, 0);
}

// ---------------- f32 -> bf16 convert (vectorized, grid-stride) ----------------
__global__ __launch_bounds__(256) void cvt_kernel(const float* __restrict__ in,
                                                  bf16* __restrict__ out, int n8) {
  int i = blockIdx.x * blockDim.x + threadIdx.x;
  int stride = gridDim.x * blockDim.x;
  for (; i < n8; i += stride) {
    const float4* p = (const float4*)in + 2 * (size_t)i;
    float4 a = p[0], b = p[1];
    bf16x8 o;
    o[0] = (bf16)a.x; o[1] = (bf16)a.y; o[2] = (bf16)a.z; o[3] = (bf16)a.w;
    o[4] = (bf16)b.x; o[5] = (bf16)b.y; o[6] = (bf16)b.z; o[7] = (bf16)b.w;
    *((bf16x8*)out + i) = o;
  }
}

// ---------------- bf16 NT GEMM: C[M][N] = A[M][K] * B[N][K]^T, C in f32 --------
// m97 structure: 128x128 tile, BK=32, 4 waves (2x2), global_load_lds width 16.
__global__ __launch_bounds__(256) void gemm_bt(const bf16* __restrict__ A,
                                               const bf16* __restrict__ B,
                                               float* __restrict__ C,
                                               int M, int N, int K) {
  __shared__ __align__(16) bf16 As[128 * 32];
  __shared__ __align__(16) bf16 Bs[128 * 32];
  const int t = threadIdx.x, l = t & 63, w = t >> 6;
  const int wm = w >> 1, wn = w & 1;
  const int l15 = l & 15, lg = l >> 4;
  const int m0 = blockIdx.y * 128, n0 = blockIdx.x * 128;

  f32x4 acc[4][4] = {};

  for (int k0 = 0; k0 < K; k0 += 32) {
#pragma unroll
    for (int j = 0; j < 2; j++) {
      int c = j * 256 + t;                 // 16B chunk index within 8KB tile
      int row = c >> 2, kc = (c & 3) * 8;  // 4 chunks per 32-elem row
      gload_lds16(A + (size_t)(m0 + row) * K + k0 + kc, As + (size_t)(j * 256 + w * 64) * 8);
      gload_lds16(B + (size_t)(n0 + row) * K + k0 + kc, Bs + (size_t)(j * 256 + w * 64) * 8);
    }
    __syncthreads();  // drains vmcnt for global_load_lds

    bf16x8 af[4], bfr[4];
#pragma unroll
    for (int i = 0; i < 4; i++)
      af[i] = *(const bf16x8*)(As + (wm * 64 + i * 16 + l15) * 32 + lg * 8);
#pragma unroll
    for (int j = 0; j < 4; j++)
      bfr[j] = *(const bf16x8*)(Bs + (wn * 64 + j * 16 + l15) * 32 + lg * 8);
#pragma unroll
    for (int i = 0; i < 4; i++)
#pragma unroll
      for (int j = 0; j < 4; j++)
        acc[i][j] = __builtin_amdgcn_mfma_f32_16x16x32_bf16(af[i], bfr[j], acc[i][j], 0, 0, 0);
    __syncthreads();
  }

#pragma unroll
  for (int i = 0; i < 4; i++) {
    int row = m0 + wm * 64 + i * 16 + lg * 4;  // C/D layout: row=(l>>4)*4+reg, col=l&15
#pragma unroll
    for (int j = 0; j < 4; j++) {
      int col = n0 + wn * 64 + j * 16 + l15;
      float* Cp = C + (size_t)row * N + col;
#pragma unroll
      for (int r = 0; r < 4; r++) Cp[(size_t)r * N] = acc[i][j][r];
    }
  }
}

// ---------------- fused RMSNorm + RoPE + layout kernel -------------------------
// QKV f32 row [6144] = [q 4096 | k 1024 | v 1024]
// Outputs: Qb[NH][S][HD], Kb[NKV][S][HD], Vt[NKV][HD][S] (bf16)
__global__ __launch_bounds__(256) void prep_kernel(const float* __restrict__ QKV,
                                                   const float* __restrict__ qw,
                                                   const float* __restrict__ kw,
                                                   const int* __restrict__ pos_ids,
                                                   bf16* __restrict__ Qb,
                                                   bf16* __restrict__ Kb,
                                                   bf16* __restrict__ Vt) {
  __shared__ __align__(16) float row[6144];
  __shared__ float cs[64];  // cos[0..31], sin[32..63]
  __shared__ float red[8];
  const int s = blockIdx.x, t = threadIdx.x;

  const float4* src = (const float4*)(QKV + (size_t)s * 6144);
#pragma unroll
  for (int i = 0; i < 6; i++) ((float4*)row)[t + i * 256] = src[t + i * 256];

  if (t < 32) {
    float p = (float)pos_ids[s];
    float ang = p * powf(10000.0f, -(float)t * (1.0f / 32.0f));
    float sn, cn;
    sincosf(ang, &sn, &cn);
    cs[t] = cn;
    cs[32 + t] = sn;
  }
  __syncthreads();

  float aq = 0.f, ak = 0.f;
  for (int i = t; i < 4096; i += 256) { float v = row[i]; aq += v * v; }
  for (int i = 4096 + t; i < 5120; i += 256) { float v = row[i]; ak += v * v; }
#pragma unroll
  for (int off = 32; off; off >>= 1) {
    aq += __shfl_down(aq, off);
    ak += __shfl_down(ak, off);
  }
  if ((t & 63) == 0) { red[t >> 6] = aq; red[4 + (t >> 6)] = ak; }
  __syncthreads();
  const float scq = rsqrtf((red[0] + red[1] + red[2] + red[3]) * (1.0f / 4096.0f) + 1e-6f);
  const float sck = rsqrtf((red[4] + red[5] + red[6] + red[7]) * (1.0f / 1024.0f) + 1e-6f);

  // q: norm + rope
  for (int e = t; e < 4096; e += 256) {
    int hh = e >> 7, d = e & 127;
    float val = row[e] * scq * qw[e];
    float o;
    if (d < 32)       o = val * cs[d] - (row[e + 32] * scq * qw[e + 32]) * cs[32 + d];
    else if (d < 64)  o = val * cs[d - 32] + (row[e - 32] * scq * qw[e - 32]) * cs[d];
    else              o = val;
    Qb[((size_t)hh * S_LEN + s) * HD + d] = (bf16)o;
  }
  // k: norm + rope
  for (int e = t; e < 1024; e += 256) {
    int hh = e >> 7, d = e & 127;
    int ri = 4096 + e;
    float val = row[ri] * sck * kw[e];
    float o;
    if (d < 32)       o = val * cs[d] - (row[ri + 32] * sck * kw[e + 32]) * cs[32 + d];
    else if (d < 64)  o = val * cs[d - 32] + (row[ri - 32] * sck * kw[e - 32]) * cs[d];
    else              o = val;
    Kb[((size_t)hh * S_LEN + s) * HD + d] = (bf16)o;
  }
  // v: transpose write
  for (int e = t; e < 1024; e += 256) {
    int hh = e >> 7, d = e & 127;
    Vt[((size_t)hh * HD + d) * S_LEN + s] = (bf16)row[5120 + e];
  }
}

// ---------------- flash attention (GQA, causal) --------------------------------
// grid (S/128, NH), 256 threads = 4 independent waves.
// Each wave owns 32 q rows (2x16 MFMA row-tiles); KVBLK=64.
// K/V read direct from global (L2-resident); V ks=0 loads issued before softmax
// to hide L2 latency under exp2/shfl; per-wave trip counts (no barriers).
__global__ __launch_bounds__(256, 2) void attn_kernel(const bf16* __restrict__ Qb,
                                                      const bf16* __restrict__ Kb,
                                                      const bf16* __restrict__ Vt,
                                                      bf16* __restrict__ Ctx) {
  __shared__ __align__(16) bf16 P[4][32][72];  // pitch 72 bf16 = 144B
  const int t = threadIdx.x, l = t & 63, w = t >> 6;
  const int l15 = l & 15, lg = l >> 4;
  const int h = blockIdx.y;
  const int q0 = blockIdx.x * 128 + w * 32;

  const bf16* Qh = Qb + ((size_t)h * S_LEN + q0) * HD;
  const bf16* Kh = Kb + (size_t)(h >> 2) * S_LEN * HD;
  const bf16* Vh = Vt + (size_t)(h >> 2) * HD * S_LEN;

  bf16x8 qf[2][4];
#pragma unroll
  for (int rt = 0; rt < 2; rt++)
#pragma unroll
    for (int kk = 0; kk < 4; kk++)
      qf[rt][kk] = *(const bf16x8*)(Qh + (size_t)(rt * 16 + l15) * HD + kk * 32 + lg * 8);

  f32x4 O[2][8] = {};
  float m[2][4], lsum[2][4];
#pragma unroll
  for (int rt = 0; rt < 2; rt++)
#pragma unroll
    for (int r = 0; r < 4; r++) { m[rt][r] = -1e30f; lsum[rt][r] = 0.f; }

  const int ntiles = (q0 >> 6) + 1;  // last tile is the only one needing a mask
  for (int tt = 0; tt < ntiles; tt++) {
    const int kv0 = tt * 64;
    // ---- QK^T: 32 MFMA, K frags shared across both row-tiles ----
    f32x4 sc[2][4];
#pragma unroll
    for (int rt = 0; rt < 2; rt++)
#pragma unroll
      for (int nt = 0; nt < 4; nt++) sc[rt][nt] = (f32x4){0.f, 0.f, 0.f, 0.f};
#pragma unroll
    for (int nt = 0; nt < 4; nt++) {
      const bf16* Kp = Kh + (size_t)(kv0 + nt * 16 + l15) * HD + lg * 8;
      bf16x8 kf[4];
#pragma unroll
      for (int kk = 0; kk < 4; kk++) kf[kk] = *(const bf16x8*)(Kp + kk * 32);
#pragma unroll
      for (int kk = 0; kk < 4; kk++) {
        sc[0][nt] = __builtin_amdgcn_mfma_f32_16x16x32_bf16(qf[0][kk], kf[kk], sc[0][nt], 0, 0, 0);
        sc[1][nt] = __builtin_amdgcn_mfma_f32_16x16x32_bf16(qf[1][kk], kf[kk], sc[1][nt], 0, 0, 0);
      }
    }
    // ---- issue V loads (first k-half) so L2 latency hides under softmax ----
    bf16x8 vf[8];
#pragma unroll
    for (int dt = 0; dt < 8; dt++)
      vf[dt] = *(const bf16x8*)(Vh + (size_t)(dt * 16 + l15) * S_LEN + kv0 + lg * 8);

    // ---- online softmax (exp2 domain) ----
    const bool lastt = (tt == ntiles - 1);
    float sv[2][4][4];
#pragma unroll
    for (int rt = 0; rt < 2; rt++)
#pragma unroll
      for (int nt = 0; nt < 4; nt++)
#pragma unroll
        for (int r = 0; r < 4; r++) {
          float x = sc[rt][nt][r] * SCALE_LOG2;
          if (lastt) {
            int kv = kv0 + nt * 16 + l15;
            int qr = q0 + rt * 16 + lg * 4 + r;
            if (kv > qr) x = -1e30f;
          }
          sv[rt][nt][r] = x;
        }
    float al[2][4];
#pragma unroll
    for (int rt = 0; rt < 2; rt++)
#pragma unroll
      for (int r = 0; r < 4; r++) {
        float x = fmaxf(fmaxf(sv[rt][0][r], sv[rt][1][r]), fmaxf(sv[rt][2][r], sv[rt][3][r]));
        x = fmaxf(x, __shfl_xor(x, 1));
        x = fmaxf(x, __shfl_xor(x, 2));
        x = fmaxf(x, __shfl_xor(x, 4));
        x = fmaxf(x, __shfl_xor(x, 8));
        float mn = fmaxf(m[rt][r], x);
        al[rt][r] = exp2f(m[rt][r] - mn);
        m[rt][r] = mn;
      }
#pragma unroll
    for (int rt = 0; rt < 2; rt++)
#pragma unroll
      for (int nt = 0; nt < 4; nt++)
#pragma unroll
        for (int r = 0; r < 4; r++) sv[rt][nt][r] = exp2f(sv[rt][nt][r] - m[rt][r]);
#pragma unroll
    for (int rt = 0; rt < 2; rt++)
#pragma unroll
      for (int r = 0; r < 4; r++) {
        float x = (sv[rt][0][r] + sv[rt][1][r]) + (sv[rt][2][r] + sv[rt][3][r]);
        x += __shfl_xor(x, 1);
        x += __shfl_xor(x, 2);
        x += __shfl_xor(x, 4);
        x += __shfl_xor(x, 8);
        lsum[rt][r] = lsum[rt][r] * al[rt][r] + x;
      }
#pragma unroll
    for (int rt = 0; rt < 2; rt++)
#pragma unroll
      for (int dt = 0; dt < 8; dt++)
#pragma unroll
        for (int r = 0; r < 4; r++) O[rt][dt][r] *= al[rt][r];

    // ---- P (C-layout) -> LDS -> A-layout fragments ----
#pragma unroll
    for (int rt = 0; rt < 2; rt++)
#pragma unroll
      for (int nt = 0; nt < 4; nt++)
#pragma unroll
        for (int r = 0; r < 4; r++)
          P[w][rt * 16 + lg * 4 + r][nt * 16 + l15] = (bf16)sv[rt][nt][r];
    asm volatile("s_waitcnt lgkmcnt(0)" ::: "memory");
    bf16x8 pa[2][2];
#pragma unroll
    for (int rt = 0; rt < 2; rt++)
#pragma unroll
      for (int ks = 0; ks < 2; ks++)
        pa[rt][ks] = *(const bf16x8*)&P[w][rt * 16 + l15][ks * 32 + lg * 8];

    // ---- PV: first k-half with prefetched V, second half loads under MFMAs ----
#pragma unroll
    for (int dt = 0; dt < 8; dt++) {
      O[0][dt] = __builtin_amdgcn_mfma_f32_16x16x32_bf16(pa[0][0], vf[dt], O[0][dt], 0, 0, 0);
      O[1][dt] = __builtin_amdgcn_mfma_f32_16x16x32_bf16(pa[1][0], vf[dt], O[1][dt], 0, 0, 0);
    }
#pragma unroll
    for (int dt = 0; dt < 8; dt++)
      vf[dt] = *(const bf16x8*)(Vh + (size_t)(dt * 16 + l15) * S_LEN + kv0 + 32 + lg * 8);
#pragma unroll
    for (int dt = 0; dt < 8; dt++) {
      O[0][dt] = __builtin_amdgcn_mfma_f32_16x16x32_bf16(pa[0][1], vf[dt], O[0][dt], 0, 0, 0);
      O[1][dt] = __builtin_amdgcn_mfma_f32_16x16x32_bf16(pa[1][1], vf[dt], O[1][dt], 0, 0, 0);
    }
  }

#pragma unroll
  for (int rt = 0; rt < 2; rt++)
#pragma unroll
    for (int r = 0; r < 4; r++) {
      float inv = 1.0f / lsum[rt][r];
      bf16* Cp = Ctx + (size_t)(q0 + rt * 16 + lg * 4 + r) * HID_D + h * HD + l15;
#pragma unroll
      for (int dt = 0; dt < 8; dt++) Cp[dt * 16] = (bf16)(O[rt][dt][r] * inv);
    }
}

// ---------------- host launcher ------------------------------------------------
extern "C" void kernel_launch(void* const* d_in, const int* in_sizes, int n_in,
                              void* d_out, int out_size, void* d_ws, size_t ws_size,
                              hipStream_t stream) {
  const float* X  = (const float*)d_in[0];
  const float* Wq = (const float*)d_in[1];
  const float* Wk = (const float*)d_in[2];
  const float* Wv = (const float*)d_in[3];
  const float* Wo = (const float*)d_in[4];
  const float* qw = (const float*)d_in[5];
  const float* kw = (const float*)d_in[6];
  const int* pos  = (const int*)d_in[7];

  char* ws = (char*)d_ws;
  bf16* Xb    = (bf16*)ws;                         // 16 MB
  bf16* Wqkvb = (bf16*)(ws + (16ll << 20));        // 48 MB: Wq|Wk|Wv contiguous
  bf16* Wob   = Wqkvb;                             // reused after GEMM1
  float* QKV  = (float*)(ws + (64ll << 20));       // 48 MB
  bf16* Ctx   = (bf16*)(ws + (64ll << 20));        // aliases QKV (after prep)
  bf16* Qb    = (bf16*)(ws + (112ll << 20));       // 16 MB
  bf16* Kb    = (bf16*)(ws + (128ll << 20));       // 4 MB
  bf16* Vt    = (bf16*)(ws + (132ll << 20));       // 4 MB

  // bf16 conversions
  cvt_kernel<<<2048, 256, 0, stream>>>(X, Xb, S_LEN * HID_D / 8);
  cvt_kernel<<<2048, 256, 0, stream>>>(Wq, Wqkvb, 4096 * 4096 / 8);
  cvt_kernel<<<512, 256, 0, stream>>>(Wk, Wqkvb + 4096 * 4096, 1024 * 4096 / 8);
  cvt_kernel<<<512, 256, 0, stream>>>(Wv, Wqkvb + 5120 * 4096, 1024 * 4096 / 8);

  // fused QKV projection: [2048 x 6144] = Xb [2048x4096] @ Wqkvb^T
  gemm_bt<<<dim3(48, 16), 256, 0, stream>>>(Xb, Wqkvb, QKV, S_LEN, 6144, HID_D);

  // Wo conversion (overwrites Wqkvb region; safe: stream-ordered after GEMM1)
  cvt_kernel<<<2048, 256, 0, stream>>>(Wo, Wob, 4096 * 4096 / 8);

  // RMSNorm + RoPE + attention layouts
  prep_kernel<<<S_LEN, 256, 0, stream>>>(QKV, qw, kw, pos, Qb, Kb, Vt);

  // flash attention (Ctx overwrites QKV region; safe after prep)
  attn_kernel<<<dim3(S_LEN / 128, NH), 256, 0, stream>>>(Qb, Kb, Vt, Ctx);

  // output projection: d_out [2048x4096] = Ctx @ Wob^T
  gemm_bt<<<dim3(32, 16), 256, 0, stream>>>(Ctx, Wob, (float*)d_out, S_LEN, HID_D, HID_D);
}

// Round 3
// 443.608 us; speedup vs baseline: 1.9267x; 1.3594x over previous
//
#include <hip/hip_runtime.h>
#include <hip/hip_bf16.h>
#include <math.h>

typedef __bf16 bf16;
typedef __bf16 bf16x8 __attribute__((ext_vector_type(8)));
typedef float f32x4 __attribute__((ext_vector_type(4)));

#define S_LEN 2048
#define HID_D 4096
#define NH 32
#define NKV 8
#define HD 128
// D^-0.5 * log2(e): softmax computed in exp2 domain
#define SCALE_LOG2 (0.08838834764831843f * 1.4426950408889634f)

__device__ __forceinline__ void gload_lds16(const void* g, void* lds) {
  __builtin_amdgcn_global_load_lds((__attribute__((address_space(1))) void*)g,
                                   (__attribute__((address_space(3))) void*)lds, 16, 0, 0);
}

#define MEMFENCE asm volatile("" ::: "memory")

// ---------------- f32 -> bf16 convert (vectorized, grid-stride) ----------------
__global__ __launch_bounds__(256) void cvt_kernel(const float* __restrict__ in,
                                                  bf16* __restrict__ out, int n8) {
  int i = blockIdx.x * blockDim.x + threadIdx.x;
  int stride = gridDim.x * blockDim.x;
  for (; i < n8; i += stride) {
    const float4* p = (const float4*)in + 2 * (size_t)i;
    float4 a = p[0], b = p[1];
    bf16x8 o;
    o[0] = (bf16)a.x; o[1] = (bf16)a.y; o[2] = (bf16)a.z; o[3] = (bf16)a.w;
    o[4] = (bf16)b.x; o[5] = (bf16)b.y; o[6] = (bf16)b.z; o[7] = (bf16)b.w;
    *((bf16x8*)out + i) = o;
  }
}

// ---------------- bf16 NT GEMM: C[M][N] = A[M][K] * B[N][K]^T, C in f32 --------
__global__ __launch_bounds__(256) void gemm_bt(const bf16* __restrict__ A,
                                               const bf16* __restrict__ B,
                                               float* __restrict__ C,
                                               int M, int N, int K) {
  __shared__ __align__(16) bf16 As[128 * 32];
  __shared__ __align__(16) bf16 Bs[128 * 32];
  const int t = threadIdx.x, l = t & 63, w = t >> 6;
  const int wm = w >> 1, wn = w & 1;
  const int l15 = l & 15, lg = l >> 4;
  const int m0 = blockIdx.y * 128, n0 = blockIdx.x * 128;

  f32x4 acc[4][4] = {};

  for (int k0 = 0; k0 < K; k0 += 32) {
#pragma unroll
    for (int j = 0; j < 2; j++) {
      int c = j * 256 + t;
      int row = c >> 2, kc = (c & 3) * 8;
      gload_lds16(A + (size_t)(m0 + row) * K + k0 + kc, As + (size_t)(j * 256 + w * 64) * 8);
      gload_lds16(B + (size_t)(n0 + row) * K + k0 + kc, Bs + (size_t)(j * 256 + w * 64) * 8);
    }
    __syncthreads();

    bf16x8 af[4], bfr[4];
#pragma unroll
    for (int i = 0; i < 4; i++)
      af[i] = *(const bf16x8*)(As + (wm * 64 + i * 16 + l15) * 32 + lg * 8);
#pragma unroll
    for (int j = 0; j < 4; j++)
      bfr[j] = *(const bf16x8*)(Bs + (wn * 64 + j * 16 + l15) * 32 + lg * 8);
#pragma unroll
    for (int i = 0; i < 4; i++)
#pragma unroll
      for (int j = 0; j < 4; j++)
        acc[i][j] = __builtin_amdgcn_mfma_f32_16x16x32_bf16(af[i], bfr[j], acc[i][j], 0, 0, 0);
    __syncthreads();
  }

#pragma unroll
  for (int i = 0; i < 4; i++) {
    int row = m0 + wm * 64 + i * 16 + lg * 4;
#pragma unroll
    for (int j = 0; j < 4; j++) {
      int col = n0 + wn * 64 + j * 16 + l15;
      float* Cp = C + (size_t)row * N + col;
#pragma unroll
      for (int r = 0; r < 4; r++) Cp[(size_t)r * N] = acc[i][j][r];
    }
  }
}

// ---------------- fused RMSNorm + RoPE + layout kernel -------------------------
__global__ __launch_bounds__(256) void prep_kernel(const float* __restrict__ QKV,
                                                   const float* __restrict__ qw,
                                                   const float* __restrict__ kw,
                                                   const int* __restrict__ pos_ids,
                                                   bf16* __restrict__ Qb,
                                                   bf16* __restrict__ Kb,
                                                   bf16* __restrict__ Vt) {
  __shared__ __align__(16) float row[6144];
  __shared__ float cs[64];
  __shared__ float red[8];
  const int s = blockIdx.x, t = threadIdx.x;

  const float4* src = (const float4*)(QKV + (size_t)s * 6144);
#pragma unroll
  for (int i = 0; i < 6; i++) ((float4*)row)[t + i * 256] = src[t + i * 256];

  if (t < 32) {
    float p = (float)pos_ids[s];
    float ang = p * powf(10000.0f, -(float)t * (1.0f / 32.0f));
    float sn, cn;
    sincosf(ang, &sn, &cn);
    cs[t] = cn;
    cs[32 + t] = sn;
  }
  __syncthreads();

  float aq = 0.f, ak = 0.f;
  for (int i = t; i < 4096; i += 256) { float v = row[i]; aq += v * v; }
  for (int i = 4096 + t; i < 5120; i += 256) { float v = row[i]; ak += v * v; }
#pragma unroll
  for (int off = 32; off; off >>= 1) {
    aq += __shfl_down(aq, off);
    ak += __shfl_down(ak, off);
  }
  if ((t & 63) == 0) { red[t >> 6] = aq; red[4 + (t >> 6)] = ak; }
  __syncthreads();
  const float scq = rsqrtf((red[0] + red[1] + red[2] + red[3]) * (1.0f / 4096.0f) + 1e-6f);
  const float sck = rsqrtf((red[4] + red[5] + red[6] + red[7]) * (1.0f / 1024.0f) + 1e-6f);

  for (int e = t; e < 4096; e += 256) {
    int d = e & 127;
    int hh = e >> 7;
    float val = row[e] * scq * qw[e];
    float o;
    if (d < 32)       o = val * cs[d] - (row[e + 32] * scq * qw[e + 32]) * cs[32 + d];
    else if (d < 64)  o = val * cs[d - 32] + (row[e - 32] * scq * qw[e - 32]) * cs[d];
    else              o = val;
    Qb[((size_t)hh * S_LEN + s) * HD + d] = (bf16)o;
  }
  for (int e = t; e < 1024; e += 256) {
    int d = e & 127;
    int hh = e >> 7;
    int ri = 4096 + e;
    float val = row[ri] * sck * kw[e];
    float o;
    if (d < 32)       o = val * cs[d] - (row[ri + 32] * sck * kw[e + 32]) * cs[32 + d];
    else if (d < 64)  o = val * cs[d - 32] + (row[ri - 32] * sck * kw[e - 32]) * cs[d];
    else              o = val;
    Kb[((size_t)hh * S_LEN + s) * HD + d] = (bf16)o;
  }
  for (int e = t; e < 1024; e += 256) {
    int d = e & 127;
    int hh = e >> 7;
    Vt[((size_t)hh * HD + d) * S_LEN + s] = (bf16)row[5120 + e];
  }
}

// ---------------- flash attention (GQA, causal, LDS-pipelined, folded) ---------
// grid = 512 blocks: blockIdx.x = pair*32 + head. Each block processes TWO
// 64-row q-chunks: c and 31-c -> uniform 33 kv-tiles per block (perfect balance,
// 2 blocks/CU). 4 waves x 16 q-rows per chunk. KV tiles (64 rows) staged in LDS:
// K double-buffered (prefetch 1 tile ahead), V single-buffered; counted
// s_waitcnt vmcnt(N) so prefetch loads stay in flight across barriers.
// All LDS XOR-swizzled (pre-swizzled global source, swizzled ds_read_b128).
__global__ __launch_bounds__(256, 2) void attn_kernel(const bf16* __restrict__ Qb,
                                                      const bf16* __restrict__ Kb,
                                                      const bf16* __restrict__ Vt,
                                                      bf16* __restrict__ Ctx) {
  __shared__ __align__(16) char KB[2][16384];  // 2 x 64 rows x 256B
  __shared__ __align__(16) char VB[16384];     // 128 rows x 128B
  __shared__ __align__(16) char PB[8192];      // 4 waves x 16 rows x 128B
  const int t = threadIdx.x, l = t & 63, w = t >> 6;
  const int l15 = l & 15, lg = l >> 4;
  const int pairc = blockIdx.x >> 5;
  const int h = blockIdx.x & 31;

  const bf16* Kh = Kb + (size_t)(h >> 2) * S_LEN * HD;
  const bf16* Vh = Vt + (size_t)(h >> 2) * HD * S_LEN;
  char* Pw = PB + w * 2048;

  // staging geometry (per thread), computed once
  const int kslot = t;              // + i*256
  const int krow0 = kslot >> 4, kj0 = kslot & 15;
  const int vrow0 = kslot >> 3, vj0 = kslot & 7;

#pragma unroll
  for (int phase = 0; phase < 2; phase++) {
    const int chunk = (phase == 0) ? pairc : (31 - pairc);
    const int ktiles = chunk + 1;
    const int q0 = chunk * 64 + w * 16;

    // Q fragments for this chunk's 16 rows
    const bf16* Qh = Qb + ((size_t)h * S_LEN + q0) * HD;
    bf16x8 qf[4];
#pragma unroll
    for (int kk = 0; kk < 4; kk++)
      qf[kk] = *(const bf16x8*)(Qh + (size_t)l15 * HD + kk * 32 + lg * 8);

    // prologue: stage K(0) into KB[0]
#pragma unroll
    for (int i = 0; i < 4; i++) {
      int r = (i * 256 + kslot) >> 4;
      const bf16* src = Kh + (size_t)r * HD + (((kj0 ^ (r & 7))) << 3);
      gload_lds16(src, KB[0] + (i * 256 + w * 64) * 16);
    }

    f32x4 O[8] = {};
    float m[4], lsum[4];
#pragma unroll
    for (int r = 0; r < 4; r++) { m[r] = -1e30f; lsum[r] = 0.f; }

    for (int tt = 0; tt < ktiles; tt++) {
      const int cur = tt & 1;
      const int kv0 = tt * 64;
      const char* Kcur = KB[cur];

      MEMFENCE;
      __builtin_amdgcn_s_barrier();  // B1: prev tile fully consumed by all waves
      MEMFENCE;

      // stage V(tt) into VB
#pragma unroll
      for (int i = 0; i < 4; i++) {
        int r = (i * 256 + kslot) >> 3;
        const bf16* src = Vh + (size_t)r * S_LEN + kv0 + ((vj0 ^ (r & 7)) << 3);
        gload_lds16(src, VB + (i * 256 + w * 64) * 16);
      }
      // stage K(tt+1) into KB[cur^1]
      if (tt + 1 < ktiles) {
#pragma unroll
        for (int i = 0; i < 4; i++) {
          int r = (i * 256 + kslot) >> 4;
          const bf16* src = Kh + (size_t)(kv0 + 64 + r) * HD + ((kj0 ^ (r & 7)) << 3);
          gload_lds16(src, KB[cur ^ 1] + (i * 256 + w * 64) * 16);
        }
        asm volatile("s_waitcnt vmcnt(8)" ::: "memory");  // K(tt) arrived; V(tt),K(tt+1) fly
      } else {
        asm volatile("s_waitcnt vmcnt(4)" ::: "memory");  // K(tt) arrived; V(tt) flies
      }

      // ---- QK^T from K-LDS: 16 MFMA ----
      f32x4 sc[4];
#pragma unroll
      for (int g = 0; g < 4; g++) sc[g] = (f32x4){0.f, 0.f, 0.f, 0.f};
#pragma unroll
      for (int g = 0; g < 4; g++) {
        const int r = g * 16 + l15;
        const char* Krow = Kcur + r * 256;
        const int sw = (r & 7);
#pragma unroll
        for (int kk = 0; kk < 4; kk++) {
          bf16x8 kf = *(const bf16x8*)(Krow + (((kk * 4 + lg) ^ sw) << 4));
          sc[g] = __builtin_amdgcn_mfma_f32_16x16x32_bf16(qf[kk], kf, sc[g], 0, 0, 0);
        }
      }

      // ---- online softmax (exp2 domain) ----
      const bool needmask = (kv0 + 63 > q0);
      float sv[4][4];
#pragma unroll
      for (int g = 0; g < 4; g++)
#pragma unroll
        for (int r = 0; r < 4; r++) {
          float x = sc[g][r] * SCALE_LOG2;
          if (needmask) {
            int kv = kv0 + g * 16 + l15;
            int qr = q0 + lg * 4 + r;
            if (kv > qr) x = -1e30f;
          }
          sv[g][r] = x;
        }
      float al[4];
#pragma unroll
      for (int r = 0; r < 4; r++) {
        float x = fmaxf(fmaxf(sv[0][r], sv[1][r]), fmaxf(sv[2][r], sv[3][r]));
        x = fmaxf(x, __shfl_xor(x, 1));
        x = fmaxf(x, __shfl_xor(x, 2));
        x = fmaxf(x, __shfl_xor(x, 4));
        x = fmaxf(x, __shfl_xor(x, 8));
        float mn = fmaxf(m[r], x);
        al[r] = exp2f(m[r] - mn);
        m[r] = mn;
      }
#pragma unroll
      for (int g = 0; g < 4; g++)
#pragma unroll
        for (int r = 0; r < 4; r++) sv[g][r] = exp2f(sv[g][r] - m[r]);
#pragma unroll
      for (int r = 0; r < 4; r++) {
        float x = (sv[0][r] + sv[1][r]) + (sv[2][r] + sv[3][r]);
        x += __shfl_xor(x, 1);
        x += __shfl_xor(x, 2);
        x += __shfl_xor(x, 4);
        x += __shfl_xor(x, 8);
        lsum[r] = lsum[r] * al[r] + x;
      }
#pragma unroll
      for (int dt = 0; dt < 8; dt++)
#pragma unroll
        for (int r = 0; r < 4; r++) O[dt][r] *= al[r];

      // ---- P -> per-wave LDS (swizzled), read back as A-fragments ----
#pragma unroll
      for (int g = 0; g < 4; g++)
#pragma unroll
        for (int r = 0; r < 4; r++) {
          int prow = lg * 4 + r;
          int pbyte = prow * 128 + (((g * 16 + l15) * 2) ^ ((prow & 7) << 4));
          *(bf16*)(Pw + pbyte) = (bf16)sv[g][r];
        }
      bf16x8 pa[2];
#pragma unroll
      for (int ks = 0; ks < 2; ks++)
        pa[ks] = *(const bf16x8*)(Pw + l15 * 128 + (((ks * 4 + lg) ^ (l15 & 7)) << 4));

      // V(tt) must be resident for all waves before PV
      if (tt + 1 < ktiles) asm volatile("s_waitcnt vmcnt(4)" ::: "memory");
      else                 asm volatile("s_waitcnt vmcnt(0)" ::: "memory");
      MEMFENCE;
      __builtin_amdgcn_s_barrier();  // B2
      MEMFENCE;

      // ---- PV from V-LDS: 16 MFMA ----
#pragma unroll
      for (int ks = 0; ks < 2; ks++)
#pragma unroll
        for (int dt = 0; dt < 8; dt++) {
          const int r = dt * 16 + l15;
          bf16x8 vf = *(const bf16x8*)(VB + r * 128 + (((ks * 4 + lg) ^ (r & 7)) << 4));
          O[dt] = __builtin_amdgcn_mfma_f32_16x16x32_bf16(pa[ks], vf, O[dt], 0, 0, 0);
        }
    }

    // ---- epilogue: normalize + write ----
#pragma unroll
    for (int r = 0; r < 4; r++) {
      float inv = 1.0f / lsum[r];
      bf16* Cp = Ctx + (size_t)(q0 + lg * 4 + r) * HID_D + h * HD + l15;
#pragma unroll
      for (int dt = 0; dt < 8; dt++) Cp[dt * 16] = (bf16)(O[dt][r] * inv);
    }
  }
}

// ---------------- host launcher ------------------------------------------------
extern "C" void kernel_launch(void* const* d_in, const int* in_sizes, int n_in,
                              void* d_out, int out_size, void* d_ws, size_t ws_size,
                              hipStream_t stream) {
  const float* X  = (const float*)d_in[0];
  const float* Wq = (const float*)d_in[1];
  const float* Wk = (const float*)d_in[2];
  const float* Wv = (const float*)d_in[3];
  const float* Wo = (const float*)d_in[4];
  const float* qw = (const float*)d_in[5];
  const float* kw = (const float*)d_in[6];
  const int* pos  = (const int*)d_in[7];

  char* ws = (char*)d_ws;
  bf16* Xb    = (bf16*)ws;                         // 16 MB
  bf16* Wqkvb = (bf16*)(ws + (16ll << 20));        // 48 MB: Wq|Wk|Wv contiguous
  bf16* Wob   = Wqkvb;                             // reused after GEMM1
  float* QKV  = (float*)(ws + (64ll << 20));       // 48 MB
  bf16* Ctx   = (bf16*)(ws + (64ll << 20));        // aliases QKV (after prep)
  bf16* Qb    = (bf16*)(ws + (112ll << 20));       // 16 MB
  bf16* Kb    = (bf16*)(ws + (128ll << 20));       // 4 MB
  bf16* Vt    = (bf16*)(ws + (132ll << 20));       // 4 MB

  // bf16 conversions
  cvt_kernel<<<2048, 256, 0, stream>>>(X, Xb, S_LEN * HID_D / 8);
  cvt_kernel<<<2048, 256, 0, stream>>>(Wq, Wqkvb, 4096 * 4096 / 8);
  cvt_kernel<<<512, 256, 0, stream>>>(Wk, Wqkvb + 4096 * 4096, 1024 * 4096 / 8);
  cvt_kernel<<<512, 256, 0, stream>>>(Wv, Wqkvb + 5120 * 4096, 1024 * 4096 / 8);

  // fused QKV projection: [2048 x 6144] = Xb [2048x4096] @ Wqkvb^T
  gemm_bt<<<dim3(48, 16), 256, 0, stream>>>(Xb, Wqkvb, QKV, S_LEN, 6144, HID_D);

  // Wo conversion (overwrites Wqkvb region; safe: stream-ordered after GEMM1)
  cvt_kernel<<<2048, 256, 0, stream>>>(Wo, Wob, 4096 * 4096 / 8);

  // RMSNorm + RoPE + attention layouts
  prep_kernel<<<S_LEN, 256, 0, stream>>>(QKV, qw, kw, pos, Qb, Kb, Vt);

  // flash attention (Ctx overwrites QKV region; safe after prep)
  attn_kernel<<<dim3(512), 256, 0, stream>>>(Qb, Kb, Vt, Ctx);

  // output projection: d_out [2048x4096] = Ctx @ Wob^T
  gemm_bt<<<dim3(32, 16), 256, 0, stream>>>(Ctx, Wob, (float*)d_out, S_LEN, HID_D, HID_D);
}

// Round 4
// 409.368 us; speedup vs baseline: 2.0879x; 1.0836x over previous
//
#include <hip/hip_runtime.h>
#include <hip/hip_bf16.h>
#include <math.h>

typedef __bf16 bf16;
typedef __bf16 bf16x8 __attribute__((ext_vector_type(8)));
typedef float f32x4 __attribute__((ext_vector_type(4)));

#define S_LEN 2048
#define HID_D 4096
#define NH 32
#define NKV 8
#define HD 128
// D^-0.5 * log2(e): softmax computed in exp2 domain
#define SCALE_LOG2 (0.08838834764831843f * 1.4426950408889634f)

__device__ __forceinline__ void gload_lds16(const void* g, void* lds) {
  __builtin_amdgcn_global_load_lds((__attribute__((address_space(1))) void*)g,
                                   (__attribute__((address_space(3))) void*)lds, 16, 0, 0);
}

#define MEMFENCE asm volatile("" ::: "memory")

// ---------------- f32 -> bf16 convert (vectorized, grid-stride) ----------------
__global__ __launch_bounds__(256) void cvt_kernel(const float* __restrict__ in,
                                                  bf16* __restrict__ out, int n8) {
  int i = blockIdx.x * blockDim.x + threadIdx.x;
  int stride = gridDim.x * blockDim.x;
  for (; i < n8; i += stride) {
    const float4* p = (const float4*)in + 2 * (size_t)i;
    float4 a = p[0], b = p[1];
    bf16x8 o;
    o[0] = (bf16)a.x; o[1] = (bf16)a.y; o[2] = (bf16)a.z; o[3] = (bf16)a.w;
    o[4] = (bf16)b.x; o[5] = (bf16)b.y; o[6] = (bf16)b.z; o[7] = (bf16)b.w;
    *((bf16x8*)out + i) = o;
  }
}

// ---------------- f32 add (split-K reduce): out += part -----------------------
__global__ __launch_bounds__(256) void add_kernel(float* __restrict__ out,
                                                  const float* __restrict__ part, int n4) {
  int i = blockIdx.x * blockDim.x + threadIdx.x;
  int stride = gridDim.x * blockDim.x;
  for (; i < n4; i += stride) {
    float4 a = ((const float4*)out)[i];
    float4 b = ((const float4*)part)[i];
    a.x += b.x; a.y += b.y; a.z += b.z; a.w += b.w;
    ((float4*)out)[i] = a;
  }
}

// ---------------- 256x256 8-phase bf16 NT GEMM --------------------------------
// C[M][N] = A[M][Kslice] * B[N][Kslice]^T over K-slice [z*Kslice, (z+1)*Kslice).
// 512 threads = 8 waves (2M x 4N), BK=64 split in 2 K-halves of 32.
// LDS 128KB: 2 dbuf x { A 2x16KB halves | B 2x16KB halves }. XOR-swizzled rows.
// Stage cadence per tile t: p1->(t+1).A.h1, p2->(t+1).B.h1 [vmcnt(8)],
// p3->(t+2).A.h0, p4->(t+2).B.h0 [vmcnt(8)]. All waits precede barriers.
__global__ __launch_bounds__(512, 2) void gemm8(const bf16* __restrict__ A,
                                                const bf16* __restrict__ B,
                                                float* __restrict__ C0,
                                                float* __restrict__ C1,
                                                int N, int Kfull, int Kslice, int T) {
  __shared__ __align__(16) char lds[131072];
  const int t = threadIdx.x, l = t & 63, w = t >> 6;
  const int wr = w >> 2, wc = w & 3;
  const int l15 = l & 15, lg = l >> 4;

  // XCD-aware swizzle (grid.x*grid.y divisible by 8 for all our launches)
  const int nwg = gridDim.x * gridDim.y;
  const int lin = blockIdx.y * gridDim.x + blockIdx.x;
  const int swz = (lin & 7) * (nwg >> 3) + (lin >> 3);
  const int n0 = (swz % gridDim.x) * 256;
  const int m0 = (swz / gridDim.x) * 256;
  const size_t kbase = (size_t)blockIdx.z * Kslice;
  float* __restrict__ C = blockIdx.z ? C1 : C0;

  // per-lane LDS read offsets (within a 16KB half: 256 rows x 64B, swizzled)
  const int lsw = l15 & 3;
  int aoff[8], boff[4];
#pragma unroll
  for (int mf = 0; mf < 8; mf++) aoff[mf] = (wr * 128 + mf * 16 + l15) * 64 + ((lg ^ lsw) << 4);
#pragma unroll
  for (int nf = 0; nf < 4; nf++) boff[nf] = (wc * 64 + nf * 16 + l15) * 64 + ((lg ^ lsw) << 4);

  // staging: half-tile = 256 rows x 32 K-elems (16KB); 2 x 16B chunks/thread
  auto stageA = [&](int d, int h, int tau) {
    char* dst = &lds[d * 65536 + h * 16384];
    size_t kpos = kbase + tau * 64 + h * 32;
#pragma unroll
    for (int i = 0; i < 2; i++) {
      int q = i * 512 + t;
      int r = q >> 2;
      int sl = (q & 3) ^ (r & 3);
      gload_lds16(A + (size_t)(m0 + r) * Kfull + kpos + sl * 8, dst + q * 16);
    }
  };
  auto stageB = [&](int d, int h, int tau) {
    char* dst = &lds[d * 65536 + 32768 + h * 16384];
    size_t kpos = kbase + tau * 64 + h * 32;
#pragma unroll
    for (int i = 0; i < 2; i++) {
      int q = i * 512 + t;
      int r = q >> 2;
      int sl = (q & 3) ^ (r & 3);
      gload_lds16(B + (size_t)(n0 + r) * Kfull + kpos + sl * 8, dst + q * 16);
    }
  };

  f32x4 acc[8][4] = {};
  bf16x8 bfr[4];

  // phase body: ds_read 4 A-frags (+4 B-frags if dob), wait, barrier, 16 MFMA, barrier
  auto phase = [&](int d, int h, int mb, bool dob, int wn) {
    bf16x8 af[4];
    const char* base = &lds[d * 65536 + h * 16384];
#pragma unroll
    for (int mf = 0; mf < 4; mf++) af[mf] = *(const bf16x8*)(base + aoff[mb + mf]);
    if (dob) {
      const char* bbase = base + 32768;
#pragma unroll
      for (int nf = 0; nf < 4; nf++) bfr[nf] = *(const bf16x8*)(bbase + boff[nf]);
    }
    if (wn == 8)      asm volatile("s_waitcnt vmcnt(8)" ::: "memory");
    else if (wn == 0) asm volatile("s_waitcnt vmcnt(0)" ::: "memory");
    MEMFENCE; __builtin_amdgcn_s_barrier(); MEMFENCE;
    asm volatile("s_waitcnt lgkmcnt(0)" ::: "memory");
    __builtin_amdgcn_sched_barrier(0);
    __builtin_amdgcn_s_setprio(1);
#pragma unroll
    for (int mf = 0; mf < 4; mf++)
#pragma unroll
      for (int nf = 0; nf < 4; nf++)
        acc[mb + mf][nf] =
            __builtin_amdgcn_mfma_f32_16x16x32_bf16(af[mf], bfr[nf], acc[mb + mf][nf], 0, 0, 0);
    __builtin_amdgcn_s_setprio(0);
    MEMFENCE; __builtin_amdgcn_s_barrier(); MEMFENCE;
  };

  // prologue: tile0 h0(A,B), h1(A,B); tile1 h0(A,B) -> 12 loads; keep newest 8
  stageA(0, 0, 0); stageB(0, 0, 0);
  stageA(0, 1, 0); stageB(0, 1, 0);
  stageA(1, 0, 1); stageB(1, 0, 1);
  asm volatile("s_waitcnt vmcnt(8)" ::: "memory");
  MEMFENCE; __builtin_amdgcn_s_barrier(); MEMFENCE;

  for (int tau = 0; tau < T; tau++) {
    const int d = tau & 1, dn = d ^ 1;
    const bool s1 = (tau + 1 < T), s2 = (tau + 2 < T);
    // p1: ks=0, mf 0-3 (+B ks0)
    if (s1) stageA(dn, 1, tau + 1);
    phase(d, 0, 0, true, -1);
    // p2: ks=0, mf 4-7
    if (s1) stageB(dn, 1, tau + 1);
    phase(d, 0, 4, false, s1 ? 8 : 0);
    // p3: ks=1, mf 0-3 (+B ks1)
    if (s2) stageA(d, 0, tau + 2);
    phase(d, 1, 0, true, -1);
    // p4: ks=1, mf 4-7
    if (s2) stageB(d, 0, tau + 2);
    phase(d, 1, 4, false, s2 ? 8 : 0);
  }

  // epilogue
#pragma unroll
  for (int mf = 0; mf < 8; mf++) {
    int row = m0 + wr * 128 + mf * 16 + lg * 4;
#pragma unroll
    for (int nf = 0; nf < 4; nf++) {
      int col = n0 + wc * 64 + nf * 16 + l15;
      float* Cp = C + (size_t)row * N + col;
#pragma unroll
      for (int rr = 0; rr < 4; rr++) Cp[(size_t)rr * N] = acc[mf][nf][rr];
    }
  }
}

// ---------------- fused RMSNorm + RoPE + layout kernel -------------------------
__global__ __launch_bounds__(256) void prep_kernel(const float* __restrict__ QKV,
                                                   const float* __restrict__ qw,
                                                   const float* __restrict__ kw,
                                                   const int* __restrict__ pos_ids,
                                                   bf16* __restrict__ Qb,
                                                   bf16* __restrict__ Kb,
                                                   bf16* __restrict__ Vt) {
  __shared__ __align__(16) float row[6144];
  __shared__ float cs[64];
  __shared__ float red[8];
  const int s = blockIdx.x, t = threadIdx.x;

  const float4* src = (const float4*)(QKV + (size_t)s * 6144);
#pragma unroll
  for (int i = 0; i < 6; i++) ((float4*)row)[t + i * 256] = src[t + i * 256];

  if (t < 32) {
    float p = (float)pos_ids[s];
    float ang = p * powf(10000.0f, -(float)t * (1.0f / 32.0f));
    float sn, cn;
    sincosf(ang, &sn, &cn);
    cs[t] = cn;
    cs[32 + t] = sn;
  }
  __syncthreads();

  float aq = 0.f, ak = 0.f;
  for (int i = t; i < 4096; i += 256) { float v = row[i]; aq += v * v; }
  for (int i = 4096 + t; i < 5120; i += 256) { float v = row[i]; ak += v * v; }
#pragma unroll
  for (int off = 32; off; off >>= 1) {
    aq += __shfl_down(aq, off);
    ak += __shfl_down(ak, off);
  }
  if ((t & 63) == 0) { red[t >> 6] = aq; red[4 + (t >> 6)] = ak; }
  __syncthreads();
  const float scq = rsqrtf((red[0] + red[1] + red[2] + red[3]) * (1.0f / 4096.0f) + 1e-6f);
  const float sck = rsqrtf((red[4] + red[5] + red[6] + red[7]) * (1.0f / 1024.0f) + 1e-6f);

  for (int e = t; e < 4096; e += 256) {
    int d = e & 127;
    int hh = e >> 7;
    float val = row[e] * scq * qw[e];
    float o;
    if (d < 32)       o = val * cs[d] - (row[e + 32] * scq * qw[e + 32]) * cs[32 + d];
    else if (d < 64)  o = val * cs[d - 32] + (row[e - 32] * scq * qw[e - 32]) * cs[d];
    else              o = val;
    Qb[((size_t)hh * S_LEN + s) * HD + d] = (bf16)o;
  }
  for (int e = t; e < 1024; e += 256) {
    int d = e & 127;
    int hh = e >> 7;
    int ri = 4096 + e;
    float val = row[ri] * sck * kw[e];
    float o;
    if (d < 32)       o = val * cs[d] - (row[ri + 32] * sck * kw[e + 32]) * cs[32 + d];
    else if (d < 64)  o = val * cs[d - 32] + (row[ri - 32] * sck * kw[e - 32]) * cs[d];
    else              o = val;
    Kb[((size_t)hh * S_LEN + s) * HD + d] = (bf16)o;
  }
  for (int e = t; e < 1024; e += 256) {
    int d = e & 127;
    int hh = e >> 7;
    Vt[((size_t)hh * HD + d) * S_LEN + s] = (bf16)row[5120 + e];
  }
}

// ---------------- flash attention (GQA, causal, LDS-pipelined, folded) ---------
// grid = 512: blockIdx.x = pair*32 + head; block does chunks (c, 31-c) of 64 q
// rows -> uniform 33 kv-tiles/block. K double-buffered, V single-buffered LDS;
// counted vmcnt ALWAYS before a barrier (cross-wave residency sound).
__global__ __launch_bounds__(256, 2) void attn_kernel(const bf16* __restrict__ Qb,
                                                      const bf16* __restrict__ Kb,
                                                      const bf16* __restrict__ Vt,
                                                      bf16* __restrict__ Ctx) {
  __shared__ __align__(16) char KB[2][16384];  // 2 x 64 rows x 256B
  __shared__ __align__(16) char VB[16384];     // 128 rows x 128B
  __shared__ __align__(16) char PB[8192];      // 4 waves x 16 rows x 128B
  const int t = threadIdx.x, l = t & 63, w = t >> 6;
  const int l15 = l & 15, lg = l >> 4;
  const int pairc = blockIdx.x >> 5;
  const int h = blockIdx.x & 31;

  const bf16* Kh = Kb + (size_t)(h >> 2) * S_LEN * HD;
  const bf16* Vh = Vt + (size_t)(h >> 2) * HD * S_LEN;
  char* Pw = PB + w * 2048;

  const int kslot = t;
  const int kj0 = kslot & 15;
  const int vj0 = kslot & 7;

#pragma unroll
  for (int phase = 0; phase < 2; phase++) {
    const int chunk = (phase == 0) ? pairc : (31 - pairc);
    const int ktiles = chunk + 1;
    const int q0 = chunk * 64 + w * 16;

    const bf16* Qh = Qb + ((size_t)h * S_LEN + q0) * HD;
    bf16x8 qf[4];
#pragma unroll
    for (int kk = 0; kk < 4; kk++)
      qf[kk] = *(const bf16x8*)(Qh + (size_t)l15 * HD + kk * 32 + lg * 8);

    // prologue: stage K(0) into KB[0]
#pragma unroll
    for (int i = 0; i < 4; i++) {
      int r = (i * 256 + kslot) >> 4;
      const bf16* src = Kh + (size_t)r * HD + (((kj0 ^ (r & 7))) << 3);
      gload_lds16(src, KB[0] + (i * 256 + w * 64) * 16);
    }

    f32x4 O[8] = {};
    float m[4], lsum[4];
#pragma unroll
    for (int r = 0; r < 4; r++) { m[r] = -1e30f; lsum[r] = 0.f; }

    for (int tt = 0; tt < ktiles; tt++) {
      const int cur = tt & 1;
      const int kv0 = tt * 64;
      const char* Kcur = KB[cur];
      const bool hasnext = (tt + 1 < ktiles);

      MEMFENCE;
      __builtin_amdgcn_s_barrier();  // B1: prev PV reads done before V overwrite
      MEMFENCE;

      // stage V(tt)
#pragma unroll
      for (int i = 0; i < 4; i++) {
        int r = (i * 256 + kslot) >> 3;
        const bf16* src = Vh + (size_t)r * S_LEN + kv0 + ((vj0 ^ (r & 7)) << 3);
        gload_lds16(src, VB + (i * 256 + w * 64) * 16);
      }
      // stage K(tt+1)
      if (hasnext) {
#pragma unroll
        for (int i = 0; i < 4; i++) {
          int r = (i * 256 + kslot) >> 4;
          const bf16* src = Kh + (size_t)(kv0 + 64 + r) * HD + ((kj0 ^ (r & 7)) << 3);
          gload_lds16(src, KB[cur ^ 1] + (i * 256 + w * 64) * 16);
        }
        asm volatile("s_waitcnt vmcnt(8)" ::: "memory");  // own K(tt) landed
      } else {
        asm volatile("s_waitcnt vmcnt(4)" ::: "memory");
      }
      MEMFENCE;
      __builtin_amdgcn_s_barrier();  // B1b: ALL waves' K(tt) resident
      MEMFENCE;

      // ---- QK^T from K-LDS ----
      f32x4 sc[4];
#pragma unroll
      for (int g = 0; g < 4; g++) sc[g] = (f32x4){0.f, 0.f, 0.f, 0.f};
#pragma unroll
      for (int g = 0; g < 4; g++) {
        const int r = g * 16 + l15;
        const char* Krow = Kcur + r * 256;
        const int sw = (r & 7);
#pragma unroll
        for (int kk = 0; kk < 4; kk++) {
          bf16x8 kf = *(const bf16x8*)(Krow + (((kk * 4 + lg) ^ sw) << 4));
          sc[g] = __builtin_amdgcn_mfma_f32_16x16x32_bf16(qf[kk], kf, sc[g], 0, 0, 0);
        }
      }

      // ---- online softmax ----
      const bool needmask = (kv0 + 63 > q0);
      float sv[4][4];
#pragma unroll
      for (int g = 0; g < 4; g++)
#pragma unroll
        for (int r = 0; r < 4; r++) {
          float x = sc[g][r] * SCALE_LOG2;
          if (needmask) {
            int kv = kv0 + g * 16 + l15;
            int qr = q0 + lg * 4 + r;
            if (kv > qr) x = -1e30f;
          }
          sv[g][r] = x;
        }
      float al[4];
#pragma unroll
      for (int r = 0; r < 4; r++) {
        float x = fmaxf(fmaxf(sv[0][r], sv[1][r]), fmaxf(sv[2][r], sv[3][r]));
        x = fmaxf(x, __shfl_xor(x, 1));
        x = fmaxf(x, __shfl_xor(x, 2));
        x = fmaxf(x, __shfl_xor(x, 4));
        x = fmaxf(x, __shfl_xor(x, 8));
        float mn = fmaxf(m[r], x);
        al[r] = exp2f(m[r] - mn);
        m[r] = mn;
      }
#pragma unroll
      for (int g = 0; g < 4; g++)
#pragma unroll
        for (int r = 0; r < 4; r++) sv[g][r] = exp2f(sv[g][r] - m[r]);
#pragma unroll
      for (int r = 0; r < 4; r++) {
        float x = (sv[0][r] + sv[1][r]) + (sv[2][r] + sv[3][r]);
        x += __shfl_xor(x, 1);
        x += __shfl_xor(x, 2);
        x += __shfl_xor(x, 4);
        x += __shfl_xor(x, 8);
        lsum[r] = lsum[r] * al[r] + x;
      }
#pragma unroll
      for (int dt = 0; dt < 8; dt++)
#pragma unroll
        for (int r = 0; r < 4; r++) O[dt][r] *= al[r];

      // ---- P -> per-wave LDS (swizzled), read back as A-fragments ----
#pragma unroll
      for (int g = 0; g < 4; g++)
#pragma unroll
        for (int r = 0; r < 4; r++) {
          int prow = lg * 4 + r;
          int pbyte = prow * 128 + (((g * 16 + l15) * 2) ^ ((prow & 7) << 4));
          *(bf16*)(Pw + pbyte) = (bf16)sv[g][r];
        }
      asm volatile("s_waitcnt lgkmcnt(0)" ::: "memory");
      bf16x8 pa[2];
#pragma unroll
      for (int ks = 0; ks < 2; ks++)
        pa[ks] = *(const bf16x8*)(Pw + l15 * 128 + (((ks * 4 + lg) ^ (l15 & 7)) << 4));

      // V(tt) resident for all waves before PV
      if (hasnext) asm volatile("s_waitcnt vmcnt(4)" ::: "memory");
      else         asm volatile("s_waitcnt vmcnt(0)" ::: "memory");
      MEMFENCE;
      __builtin_amdgcn_s_barrier();  // B2
      MEMFENCE;

      // ---- PV from V-LDS ----
#pragma unroll
      for (int ks = 0; ks < 2; ks++)
#pragma unroll
        for (int dt = 0; dt < 8; dt++) {
          const int r = dt * 16 + l15;
          bf16x8 vf = *(const bf16x8*)(VB + r * 128 + (((ks * 4 + lg) ^ (r & 7)) << 4));
          O[dt] = __builtin_amdgcn_mfma_f32_16x16x32_bf16(pa[ks], vf, O[dt], 0, 0, 0);
        }
    }

    // ---- epilogue ----
#pragma unroll
    for (int r = 0; r < 4; r++) {
      float inv = 1.0f / lsum[r];
      bf16* Cp = Ctx + (size_t)(q0 + lg * 4 + r) * HID_D + h * HD + l15;
#pragma unroll
      for (int dt = 0; dt < 8; dt++) Cp[dt * 16] = (bf16)(O[dt][r] * inv);
    }
  }
}

// ---------------- host launcher ------------------------------------------------
extern "C" void kernel_launch(void* const* d_in, const int* in_sizes, int n_in,
                              void* d_out, int out_size, void* d_ws, size_t ws_size,
                              hipStream_t stream) {
  const float* X  = (const float*)d_in[0];
  const float* Wq = (const float*)d_in[1];
  const float* Wk = (const float*)d_in[2];
  const float* Wv = (const float*)d_in[3];
  const float* Wo = (const float*)d_in[4];
  const float* qw = (const float*)d_in[5];
  const float* kw = (const float*)d_in[6];
  const int* pos  = (const int*)d_in[7];

  char* ws = (char*)d_ws;
  bf16* Xb    = (bf16*)ws;                         // [0,16): X bf16
  bf16* Wqkvb = (bf16*)(ws + (16ll << 20));        // [16,64): Wq|Wk|Wv (later Wo)
  bf16* Wob   = Wqkvb;
  float* QKV  = (float*)(ws + (64ll << 20));       // [64,112): QKV f32 (dead after prep)
  float* Part = (float*)(ws + (64ll << 20));       // [64,96): out-proj split-K partial
  bf16* Ctx   = (bf16*)(ws + (96ll << 20));        // [96,112): attn output bf16
  bf16* Qb    = (bf16*)(ws + (112ll << 20));       // [112,128)
  bf16* Kb    = (bf16*)(ws + (128ll << 20));       // [128,132)
  bf16* Vt    = (bf16*)(ws + (132ll << 20));       // [132,136)

  // bf16 conversions
  cvt_kernel<<<2048, 256, 0, stream>>>(X, Xb, S_LEN * HID_D / 8);
  cvt_kernel<<<2048, 256, 0, stream>>>(Wq, Wqkvb, 4096 * 4096 / 8);
  cvt_kernel<<<512, 256, 0, stream>>>(Wk, Wqkvb + 4096 * 4096, 1024 * 4096 / 8);
  cvt_kernel<<<512, 256, 0, stream>>>(Wv, Wqkvb + 5120 * 4096, 1024 * 4096 / 8);

  // fused QKV projection: [2048 x 6144] = Xb @ Wqkvb^T  (192 blocks)
  gemm8<<<dim3(24, 8, 1), 512, 0, stream>>>(Xb, Wqkvb, QKV, QKV, 6144, HID_D, HID_D, 64);

  // Wo conversion (overwrites Wqkvb; stream-ordered after QKV GEMM)
  cvt_kernel<<<2048, 256, 0, stream>>>(Wo, Wob, 4096 * 4096 / 8);

  // RMSNorm + RoPE + attention layouts
  prep_kernel<<<S_LEN, 256, 0, stream>>>(QKV, qw, kw, pos, Qb, Kb, Vt);

  // flash attention
  attn_kernel<<<dim3(512), 256, 0, stream>>>(Qb, Kb, Vt, Ctx);

  // output projection, split-K=2: z=0 -> d_out, z=1 -> Part; then reduce
  gemm8<<<dim3(16, 8, 2), 512, 0, stream>>>(Ctx, Wob, (float*)d_out, Part,
                                            HID_D, HID_D, 2048, 32);
  add_kernel<<<2048, 256, 0, stream>>>((float*)d_out, Part, S_LEN * HID_D / 4);
}

// Round 5
// 388.140 us; speedup vs baseline: 2.2021x; 1.0547x over previous
//
#include <hip/hip_runtime.h>
#include <hip/hip_bf16.h>
#include <math.h>

typedef __bf16 bf16;
typedef __bf16 bf16x8 __attribute__((ext_vector_type(8)));
typedef float f32x4 __attribute__((ext_vector_type(4)));

#define S_LEN 2048
#define HID_D 4096
#define NH 32
#define NKV 8
#define HD 128
// D^-0.5 * log2(e): softmax computed in exp2 domain
#define SCALE_LOG2 (0.08838834764831843f * 1.4426950408889634f)

__device__ __forceinline__ void gload_lds16(const void* g, void* lds) {
  __builtin_amdgcn_global_load_lds((__attribute__((address_space(1))) void*)g,
                                   (__attribute__((address_space(3))) void*)lds, 16, 0, 0);
}

#define MEMFENCE asm volatile("" ::: "memory")

// ---------------- f32 -> bf16 convert (vectorized, grid-stride) ----------------
__global__ __launch_bounds__(256) void cvt_kernel(const float* __restrict__ in,
                                                  bf16* __restrict__ out, int n8) {
  int i = blockIdx.x * blockDim.x + threadIdx.x;
  int stride = gridDim.x * blockDim.x;
  for (; i < n8; i += stride) {
    const float4* p = (const float4*)in + 2 * (size_t)i;
    float4 a = p[0], b = p[1];
    bf16x8 o;
    o[0] = (bf16)a.x; o[1] = (bf16)a.y; o[2] = (bf16)a.z; o[3] = (bf16)a.w;
    o[4] = (bf16)b.x; o[5] = (bf16)b.y; o[6] = (bf16)b.z; o[7] = (bf16)b.w;
    *((bf16x8*)out + i) = o;
  }
}

// ---------------- f32 add (split-K reduce): out += part -----------------------
__global__ __launch_bounds__(256) void add_kernel(float* __restrict__ out,
                                                  const float* __restrict__ part, int n4) {
  int i = blockIdx.x * blockDim.x + threadIdx.x;
  int stride = gridDim.x * blockDim.x;
  for (; i < n4; i += stride) {
    float4 a = ((const float4*)out)[i];
    float4 b = ((const float4*)part)[i];
    a.x += b.x; a.y += b.y; a.z += b.z; a.w += b.w;
    ((float4*)out)[i] = a;
  }
}

// ---------------- templated 8-phase bf16 NT GEMM -------------------------------
// C[M][N] = A[M][Ks] * B[N][Ks]^T over K-slice [z*Kslice, (z+1)*Kslice).
// 512 threads = 8 waves (2M x 4N); wave tile (BM/2)x(BN/4); BK=64 (2 halves).
// LDS = 2 dbuf x { A 2x(BM*64B) halves | B 2x(BN*64B) halves } = 128KB for
// BM+BN=512. Swizzle: 16B-chunk c at row r stored/read at c ^ ((r>>1)&3) ->
// granule class 4*(r&1) + (c^((r>>1)&3)) covers all 8 classes (2-way = free).
// Stage cadence per tile t: p1->(t+1).A.h1, p2->(t+1).B.h1 [vmcnt(8)],
// p3->(t+2).A.h0, p4->(t+2).B.h0 [vmcnt(8)]. L=4 loads/half for both shapes.
template <int BM, int BN>
__global__ __launch_bounds__(512, 2) void gemm8(const bf16* __restrict__ A,
                                                const bf16* __restrict__ B,
                                                float* __restrict__ C0,
                                                float* __restrict__ C1,
                                                int N, int Kfull, int Kslice, int T) {
  constexpr int MF = BM / 32;       // A frags per wave (16-row units)
  constexpr int NF = BN / 64;       // B frags per wave
  constexpr int AL = BM / 128;      // gload insts per A-half
  constexpr int BL = BN / 128;      // gload insts per B-half
  constexpr int AH = BM * 64;       // A-half bytes
  constexpr int BH = BN * 64;       // B-half bytes
  constexpr int DBUF = 2 * (AH + BH);

  __shared__ __align__(16) char lds[2 * DBUF];
  const int t = threadIdx.x, l = t & 63, w = t >> 6;
  const int wr = w >> 2, wc = w & 3;
  const int l15 = l & 15, lg = l >> 4;

  // XCD-aware swizzle (nwg per z-slice divisible by 8 for all launches)
  const int nwg = gridDim.x * gridDim.y;
  const int lin = blockIdx.y * gridDim.x + blockIdx.x;
  const int swz = (lin & 7) * (nwg >> 3) + (lin >> 3);
  const int n0 = (swz % gridDim.x) * BN;
  const int m0 = (swz / gridDim.x) * BM;
  const size_t kbase = (size_t)blockIdx.z * Kslice;
  float* __restrict__ C = blockIdx.z ? C1 : C0;

  // per-lane LDS read offsets within a half (row*64B, swizzled chunk)
  int aoffs[MF], boffs[NF];
#pragma unroll
  for (int m = 0; m < MF; m++) {
    int row = wr * (BM / 2) + m * 16 + l15;
    aoffs[m] = row * 64 + ((lg ^ ((row >> 1) & 3)) << 4);
  }
#pragma unroll
  for (int n = 0; n < NF; n++) {
    int row = wc * (BN / 4) + n * 16 + l15;
    boffs[n] = row * 64 + ((lg ^ ((row >> 1) & 3)) << 4);
  }

  auto stageA = [&](int d, int h, int tau) {
    char* dst = lds + d * DBUF + h * AH;
    size_t kpos = kbase + tau * 64 + h * 32;
#pragma unroll
    for (int i = 0; i < AL; i++) {
      int q = i * 512 + t;
      int r = q >> 2;
      int sl = (q & 3) ^ ((r >> 1) & 3);
      gload_lds16(A + (size_t)(m0 + r) * Kfull + kpos + sl * 8, dst + q * 16);
    }
  };
  auto stageB = [&](int d, int h, int tau) {
    char* dst = lds + d * DBUF + 2 * AH + h * BH;
    size_t kpos = kbase + tau * 64 + h * 32;
#pragma unroll
    for (int i = 0; i < BL; i++) {
      int q = i * 512 + t;
      int r = q >> 2;
      int sl = (q & 3) ^ ((r >> 1) & 3);
      gload_lds16(B + (size_t)(n0 + r) * Kfull + kpos + sl * 8, dst + q * 16);
    }
  };

  f32x4 acc[MF][NF] = {};
  bf16x8 bfr[NF];

  auto phase = [&](int d, int h, int mb, bool dob, int wn) {
    bf16x8 af[MF / 2];
    const char* abase = lds + d * DBUF + h * AH;
#pragma unroll
    for (int mf = 0; mf < MF / 2; mf++) af[mf] = *(const bf16x8*)(abase + aoffs[mb + mf]);
    if (dob) {
      const char* bbase = lds + d * DBUF + 2 * AH + h * BH;
#pragma unroll
      for (int nf = 0; nf < NF; nf++) bfr[nf] = *(const bf16x8*)(bbase + boffs[nf]);
    }
    if (wn == 8)      asm volatile("s_waitcnt vmcnt(8)" ::: "memory");
    else if (wn == 4) asm volatile("s_waitcnt vmcnt(4)" ::: "memory");
    else if (wn == 0) asm volatile("s_waitcnt vmcnt(0)" ::: "memory");
    MEMFENCE; __builtin_amdgcn_s_barrier(); MEMFENCE;
    asm volatile("s_waitcnt lgkmcnt(0)" ::: "memory");
    __builtin_amdgcn_sched_barrier(0);
    __builtin_amdgcn_s_setprio(1);
#pragma unroll
    for (int mf = 0; mf < MF / 2; mf++)
#pragma unroll
      for (int nf = 0; nf < NF; nf++)
        acc[mb + mf][nf] =
            __builtin_amdgcn_mfma_f32_16x16x32_bf16(af[mf], bfr[nf], acc[mb + mf][nf], 0, 0, 0);
    __builtin_amdgcn_s_setprio(0);
    MEMFENCE; __builtin_amdgcn_s_barrier(); MEMFENCE;
  };

  // prologue: t0.h0, t0.h1, t1.h0 (12 loads/wave); drain t0.h0 (keep newest 8)
  stageA(0, 0, 0); stageB(0, 0, 0);
  stageA(0, 1, 0); stageB(0, 1, 0);
  stageA(1, 0, 1); stageB(1, 0, 1);
  asm volatile("s_waitcnt vmcnt(8)" ::: "memory");
  MEMFENCE; __builtin_amdgcn_s_barrier(); MEMFENCE;

  for (int tau = 0; tau < T; tau++) {
    const int d = tau & 1, dn = d ^ 1;
    const bool s1 = (tau + 1 < T), s2 = (tau + 2 < T);
    if (s1) stageA(dn, 1, tau + 1);
    phase(d, 0, 0, true, -1);
    if (s1) stageB(dn, 1, tau + 1);
    phase(d, 0, MF / 2, false, s1 ? 8 : 0);          // drains tau.h1
    if (s2) stageA(d, 0, tau + 2);
    phase(d, 1, 0, true, -1);
    if (s2) stageB(d, 0, tau + 2);
    phase(d, 1, MF / 2, false, s2 ? 8 : (s1 ? 4 : -1));  // drains (tau+1).h0
  }

  // epilogue
#pragma unroll
  for (int mf = 0; mf < MF; mf++) {
    int row = m0 + wr * (BM / 2) + mf * 16 + lg * 4;
#pragma unroll
    for (int nf = 0; nf < NF; nf++) {
      int col = n0 + wc * (BN / 4) + nf * 16 + l15;
      float* Cp = C + (size_t)row * N + col;
#pragma unroll
      for (int rr = 0; rr < 4; rr++) Cp[(size_t)rr * N] = acc[mf][nf][rr];
    }
  }
}

// ---------------- fused RMSNorm + RoPE + layout kernel -------------------------
__global__ __launch_bounds__(256) void prep_kernel(const float* __restrict__ QKV,
                                                   const float* __restrict__ qw,
                                                   const float* __restrict__ kw,
                                                   const int* __restrict__ pos_ids,
                                                   bf16* __restrict__ Qb,
                                                   bf16* __restrict__ Kb,
                                                   bf16* __restrict__ Vt) {
  __shared__ __align__(16) float row[6144];
  __shared__ float cs[64];
  __shared__ float red[8];
  const int s = blockIdx.x, t = threadIdx.x;

  const float4* src = (const float4*)(QKV + (size_t)s * 6144);
#pragma unroll
  for (int i = 0; i < 6; i++) ((float4*)row)[t + i * 256] = src[t + i * 256];

  if (t < 32) {
    float p = (float)pos_ids[s];
    float ang = p * powf(10000.0f, -(float)t * (1.0f / 32.0f));
    float sn, cn;
    sincosf(ang, &sn, &cn);
    cs[t] = cn;
    cs[32 + t] = sn;
  }
  __syncthreads();

  float aq = 0.f, ak = 0.f;
  for (int i = t; i < 4096; i += 256) { float v = row[i]; aq += v * v; }
  for (int i = 4096 + t; i < 5120; i += 256) { float v = row[i]; ak += v * v; }
#pragma unroll
  for (int off = 32; off; off >>= 1) {
    aq += __shfl_down(aq, off);
    ak += __shfl_down(ak, off);
  }
  if ((t & 63) == 0) { red[t >> 6] = aq; red[4 + (t >> 6)] = ak; }
  __syncthreads();
  const float scq = rsqrtf((red[0] + red[1] + red[2] + red[3]) * (1.0f / 4096.0f) + 1e-6f);
  const float sck = rsqrtf((red[4] + red[5] + red[6] + red[7]) * (1.0f / 1024.0f) + 1e-6f);

  for (int e = t; e < 4096; e += 256) {
    int d = e & 127;
    int hh = e >> 7;
    float val = row[e] * scq * qw[e];
    float o;
    if (d < 32)       o = val * cs[d] - (row[e + 32] * scq * qw[e + 32]) * cs[32 + d];
    else if (d < 64)  o = val * cs[d - 32] + (row[e - 32] * scq * qw[e - 32]) * cs[d];
    else              o = val;
    Qb[((size_t)hh * S_LEN + s) * HD + d] = (bf16)o;
  }
  for (int e = t; e < 1024; e += 256) {
    int d = e & 127;
    int hh = e >> 7;
    int ri = 4096 + e;
    float val = row[ri] * sck * kw[e];
    float o;
    if (d < 32)       o = val * cs[d] - (row[ri + 32] * sck * kw[e + 32]) * cs[32 + d];
    else if (d < 64)  o = val * cs[d - 32] + (row[ri - 32] * sck * kw[e - 32]) * cs[d];
    else              o = val;
    Kb[((size_t)hh * S_LEN + s) * HD + d] = (bf16)o;
  }
  for (int e = t; e < 1024; e += 256) {
    int d = e & 127;
    int hh = e >> 7;
    Vt[((size_t)hh * HD + d) * S_LEN + s] = (bf16)row[5120 + e];
  }
}

// ---------------- flash attention (GQA, causal, LDS-pipelined, folded) ---------
__global__ __launch_bounds__(256, 2) void attn_kernel(const bf16* __restrict__ Qb,
                                                      const bf16* __restrict__ Kb,
                                                      const bf16* __restrict__ Vt,
                                                      bf16* __restrict__ Ctx) {
  __shared__ __align__(16) char KB[2][16384];  // 2 x 64 rows x 256B
  __shared__ __align__(16) char VB[16384];     // 128 rows x 128B
  __shared__ __align__(16) char PB[8192];      // 4 waves x 16 rows x 128B
  const int t = threadIdx.x, l = t & 63, w = t >> 6;
  const int l15 = l & 15, lg = l >> 4;
  const int pairc = blockIdx.x >> 5;
  const int h = blockIdx.x & 31;

  const bf16* Kh = Kb + (size_t)(h >> 2) * S_LEN * HD;
  const bf16* Vh = Vt + (size_t)(h >> 2) * HD * S_LEN;
  char* Pw = PB + w * 2048;

  const int kslot = t;
  const int kj0 = kslot & 15;
  const int vj0 = kslot & 7;

#pragma unroll
  for (int phase = 0; phase < 2; phase++) {
    const int chunk = (phase == 0) ? pairc : (31 - pairc);
    const int ktiles = chunk + 1;
    const int q0 = chunk * 64 + w * 16;

    const bf16* Qh = Qb + ((size_t)h * S_LEN + q0) * HD;
    bf16x8 qf[4];
#pragma unroll
    for (int kk = 0; kk < 4; kk++)
      qf[kk] = *(const bf16x8*)(Qh + (size_t)l15 * HD + kk * 32 + lg * 8);

    // prologue: stage K(0) into KB[0]
#pragma unroll
    for (int i = 0; i < 4; i++) {
      int r = (i * 256 + kslot) >> 4;
      const bf16* src = Kh + (size_t)r * HD + (((kj0 ^ (r & 7))) << 3);
      gload_lds16(src, KB[0] + (i * 256 + w * 64) * 16);
    }

    f32x4 O[8] = {};
    float m[4], lsum[4];
#pragma unroll
    for (int r = 0; r < 4; r++) { m[r] = -1e30f; lsum[r] = 0.f; }

    for (int tt = 0; tt < ktiles; tt++) {
      const int cur = tt & 1;
      const int kv0 = tt * 64;
      const char* Kcur = KB[cur];
      const bool hasnext = (tt + 1 < ktiles);

      MEMFENCE;
      __builtin_amdgcn_s_barrier();  // B1: prev PV reads done before V overwrite
      MEMFENCE;

      // stage V(tt)
#pragma unroll
      for (int i = 0; i < 4; i++) {
        int r = (i * 256 + kslot) >> 3;
        const bf16* src = Vh + (size_t)r * S_LEN + kv0 + ((vj0 ^ (r & 7)) << 3);
        gload_lds16(src, VB + (i * 256 + w * 64) * 16);
      }
      // stage K(tt+1)
      if (hasnext) {
#pragma unroll
        for (int i = 0; i < 4; i++) {
          int r = (i * 256 + kslot) >> 4;
          const bf16* src = Kh + (size_t)(kv0 + 64 + r) * HD + ((kj0 ^ (r & 7)) << 3);
          gload_lds16(src, KB[cur ^ 1] + (i * 256 + w * 64) * 16);
        }
        asm volatile("s_waitcnt vmcnt(8)" ::: "memory");
      } else {
        asm volatile("s_waitcnt vmcnt(4)" ::: "memory");
      }
      MEMFENCE;
      __builtin_amdgcn_s_barrier();  // B1b: ALL waves' K(tt) resident
      MEMFENCE;

      // ---- QK^T from K-LDS ----
      f32x4 sc[4];
#pragma unroll
      for (int g = 0; g < 4; g++) sc[g] = (f32x4){0.f, 0.f, 0.f, 0.f};
#pragma unroll
      for (int g = 0; g < 4; g++) {
        const int r = g * 16 + l15;
        const char* Krow = Kcur + r * 256;
        const int sw = (r & 7);
#pragma unroll
        for (int kk = 0; kk < 4; kk++) {
          bf16x8 kf = *(const bf16x8*)(Krow + (((kk * 4 + lg) ^ sw) << 4));
          sc[g] = __builtin_amdgcn_mfma_f32_16x16x32_bf16(qf[kk], kf, sc[g], 0, 0, 0);
        }
      }

      // ---- online softmax ----
      const bool needmask = (kv0 + 63 > q0);
      float sv[4][4];
#pragma unroll
      for (int g = 0; g < 4; g++)
#pragma unroll
        for (int r = 0; r < 4; r++) {
          float x = sc[g][r] * SCALE_LOG2;
          if (needmask) {
            int kv = kv0 + g * 16 + l15;
            int qr = q0 + lg * 4 + r;
            if (kv > qr) x = -1e30f;
          }
          sv[g][r] = x;
        }
      float al[4];
#pragma unroll
      for (int r = 0; r < 4; r++) {
        float x = fmaxf(fmaxf(sv[0][r], sv[1][r]), fmaxf(sv[2][r], sv[3][r]));
        x = fmaxf(x, __shfl_xor(x, 1));
        x = fmaxf(x, __shfl_xor(x, 2));
        x = fmaxf(x, __shfl_xor(x, 4));
        x = fmaxf(x, __shfl_xor(x, 8));
        float mn = fmaxf(m[r], x);
        al[r] = exp2f(m[r] - mn);
        m[r] = mn;
      }
#pragma unroll
      for (int g = 0; g < 4; g++)
#pragma unroll
        for (int r = 0; r < 4; r++) sv[g][r] = exp2f(sv[g][r] - m[r]);
#pragma unroll
      for (int r = 0; r < 4; r++) {
        float x = (sv[0][r] + sv[1][r]) + (sv[2][r] + sv[3][r]);
        x += __shfl_xor(x, 1);
        x += __shfl_xor(x, 2);
        x += __shfl_xor(x, 4);
        x += __shfl_xor(x, 8);
        lsum[r] = lsum[r] * al[r] + x;
      }
#pragma unroll
      for (int dt = 0; dt < 8; dt++)
#pragma unroll
        for (int r = 0; r < 4; r++) O[dt][r] *= al[r];

      // ---- P -> per-wave LDS (swizzled), read back as A-fragments ----
#pragma unroll
      for (int g = 0; g < 4; g++)
#pragma unroll
        for (int r = 0; r < 4; r++) {
          int prow = lg * 4 + r;
          int pbyte = prow * 128 + (((g * 16 + l15) * 2) ^ ((prow & 7) << 4));
          *(bf16*)(Pw + pbyte) = (bf16)sv[g][r];
        }
      asm volatile("s_waitcnt lgkmcnt(0)" ::: "memory");
      bf16x8 pa[2];
#pragma unroll
      for (int ks = 0; ks < 2; ks++)
        pa[ks] = *(const bf16x8*)(Pw + l15 * 128 + (((ks * 4 + lg) ^ (l15 & 7)) << 4));

      // V(tt) resident for all waves before PV
      if (hasnext) asm volatile("s_waitcnt vmcnt(4)" ::: "memory");
      else         asm volatile("s_waitcnt vmcnt(0)" ::: "memory");
      MEMFENCE;
      __builtin_amdgcn_s_barrier();  // B2
      MEMFENCE;

      // ---- PV from V-LDS ----
#pragma unroll
      for (int ks = 0; ks < 2; ks++)
#pragma unroll
        for (int dt = 0; dt < 8; dt++) {
          const int r = dt * 16 + l15;
          bf16x8 vf = *(const bf16x8*)(VB + r * 128 + (((ks * 4 + lg) ^ (r & 7)) << 4));
          O[dt] = __builtin_amdgcn_mfma_f32_16x16x32_bf16(pa[ks], vf, O[dt], 0, 0, 0);
        }
    }

    // ---- epilogue ----
#pragma unroll
    for (int r = 0; r < 4; r++) {
      float inv = 1.0f / lsum[r];
      bf16* Cp = Ctx + (size_t)(q0 + lg * 4 + r) * HID_D + h * HD + l15;
#pragma unroll
      for (int dt = 0; dt < 8; dt++) Cp[dt * 16] = (bf16)(O[dt][r] * inv);
    }
  }
}

// ---------------- host launcher ------------------------------------------------
extern "C" void kernel_launch(void* const* d_in, const int* in_sizes, int n_in,
                              void* d_out, int out_size, void* d_ws, size_t ws_size,
                              hipStream_t stream) {
  const float* X  = (const float*)d_in[0];
  const float* Wq = (const float*)d_in[1];
  const float* Wk = (const float*)d_in[2];
  const float* Wv = (const float*)d_in[3];
  const float* Wo = (const float*)d_in[4];
  const float* qw = (const float*)d_in[5];
  const float* kw = (const float*)d_in[6];
  const int* pos  = (const int*)d_in[7];

  char* ws = (char*)d_ws;
  bf16* Xb    = (bf16*)ws;                         // [0,16): X bf16
  bf16* Wqkvb = (bf16*)(ws + (16ll << 20));        // [16,64): Wq|Wk|Wv (later Wo)
  bf16* Wob   = Wqkvb;
  float* QKV  = (float*)(ws + (64ll << 20));       // [64,112): QKV f32 (dead after prep)
  float* Part = (float*)(ws + (64ll << 20));       // [64,96): out-proj split-K partial
  bf16* Ctx   = (bf16*)(ws + (96ll << 20));        // [96,112): attn output bf16
  bf16* Qb    = (bf16*)(ws + (112ll << 20));       // [112,128)
  bf16* Kb    = (bf16*)(ws + (128ll << 20));       // [128,132)
  bf16* Vt    = (bf16*)(ws + (132ll << 20));       // [132,136)

  // bf16 conversions
  cvt_kernel<<<2048, 256, 0, stream>>>(X, Xb, S_LEN * HID_D / 8);
  cvt_kernel<<<2048, 256, 0, stream>>>(Wq, Wqkvb, 4096 * 4096 / 8);
  cvt_kernel<<<512, 256, 0, stream>>>(Wk, Wqkvb + 4096 * 4096, 1024 * 4096 / 8);
  cvt_kernel<<<512, 256, 0, stream>>>(Wv, Wqkvb + 5120 * 4096, 1024 * 4096 / 8);

  // fused QKV projection: [2048 x 6144] = Xb @ Wqkvb^T; 128x384 tiles, 256 blocks
  gemm8<128, 384><<<dim3(16, 16, 1), 512, 0, stream>>>(Xb, Wqkvb, QKV, QKV,
                                                       6144, HID_D, HID_D, 64);

  // Wo conversion (overwrites Wqkvb; stream-ordered after QKV GEMM)
  cvt_kernel<<<2048, 256, 0, stream>>>(Wo, Wob, 4096 * 4096 / 8);

  // RMSNorm + RoPE + attention layouts
  prep_kernel<<<S_LEN, 256, 0, stream>>>(QKV, qw, kw, pos, Qb, Kb, Vt);

  // flash attention
  attn_kernel<<<dim3(512), 256, 0, stream>>>(Qb, Kb, Vt, Ctx);

  // output projection, split-K=2: z=0 -> d_out, z=1 -> Part; then reduce
  gemm8<256, 256><<<dim3(16, 8, 2), 512, 0, stream>>>(Ctx, Wob, (float*)d_out, Part,
                                                      HID_D, HID_D, 2048, 32);
  add_kernel<<<2048, 256, 0, stream>>>((float*)d_out, Part, S_LEN * HID_D / 4);
}